// Round 1
// baseline (1627.766 us; speedup 1.0000x reference)
//
#include <hip/hip_runtime.h>

// ---------- helpers ----------

__device__ __forceinline__ float waveSum(float v) {
#pragma unroll
    for (int off = 32; off > 0; off >>= 1)
        v += __shfl_xor(v, off, 64);
    return v;
}

// monotone float <-> uint key for atomicMax on floats (incl. negatives)
__device__ __forceinline__ unsigned int fkey(float f) {
    unsigned int b = __float_as_uint(f);
    return (b & 0x80000000u) ? ~b : (b | 0x80000000u);
}
__device__ __forceinline__ float funkey(unsigned int k) {
    unsigned int b = (k & 0x80000000u) ? (k ^ 0x80000000u) : ~k;
    return __uint_as_float(b);
}

// ---------- kernels ----------

// w_all[r][k] = sum_c W_Q[k][c] * relemb[r][c]  for r=0..8 (edge_type-1)
// w_all[9][k] = sum_c W_UI[k][c] * relemb[edge_type[E-1]-1][c]   (rel_last)
__global__ void compute_w_kernel(const float* __restrict__ WQ,
                                 const float* __restrict__ WUI,
                                 const float* __restrict__ relemb,
                                 const int* __restrict__ etype, int Ekg,
                                 float* __restrict__ w_all) {
    int k = threadIdx.x; // 0..63
    for (int r = 0; r < 9; ++r) {
        float acc = 0.f;
#pragma unroll
        for (int c = 0; c < 64; ++c)
            acc = fmaf(WQ[k * 64 + c], relemb[r * 64 + c], acc);
        w_all[r * 64 + k] = acc;
    }
    int rl = etype[Ekg - 1] - 1;
    float acc = 0.f;
#pragma unroll
    for (int c = 0; c < 64; ++c)
        acc = fmaf(WUI[k * 64 + c], relemb[rl * 64 + c], acc);
    w_all[9 * 64 + k] = acc;
}

// S[i*10 + r] = E[i] . w_all[r]   (r=0..8 KG relations, r=9 -> UI key table)
__global__ void entity_tables_kernel(const float* __restrict__ E, int n_ent,
                                     const float* __restrict__ w_all,
                                     float* __restrict__ S) {
    __shared__ float w[640];
    for (int i = threadIdx.x; i < 640; i += blockDim.x) w[i] = w_all[i];
    __syncthreads();
    int wid = blockIdx.x * 4 + (threadIdx.x >> 6);
    int lane = threadIdx.x & 63;
    if (wid >= n_ent) return;
    float e = E[(size_t)wid * 64 + lane];
    float d[10];
#pragma unroll
    for (int r = 0; r < 10; ++r)
        d[r] = waveSum(e * w[r * 64 + lane]);
    if (lane == 0) {
#pragma unroll
        for (int r = 0; r < 10; ++r)
            S[(size_t)wid * 10 + r] = d[r];
    }
}

// su[u] = U[u] . w_all[9]
__global__ void user_table_kernel(const float* __restrict__ U, int n_usr,
                                  const float* __restrict__ w_all,
                                  float* __restrict__ su) {
    __shared__ float w[64];
    if (threadIdx.x < 64) w[threadIdx.x] = w_all[9 * 64 + threadIdx.x];
    __syncthreads();
    int wid = blockIdx.x * 4 + (threadIdx.x >> 6);
    int lane = threadIdx.x & 63;
    if (wid >= n_usr) return;
    float v = waveSum(U[(size_t)wid * 64 + lane] * w[lane]);
    if (lane == 0) su[wid] = v;
}

__global__ void kg_pass1_kernel(const int* __restrict__ head,
                                const int* __restrict__ tail,
                                const int* __restrict__ etype,
                                const float* __restrict__ S, int E,
                                float* __restrict__ score,
                                unsigned int* __restrict__ mkey) {
    int e = blockIdx.x * blockDim.x + threadIdx.x;
    if (e >= E) return;
    int h = head[e], t = tail[e], r = etype[e] - 1;
    float sc = S[(size_t)h * 10 + r] + S[(size_t)t * 10 + r];
    score[e] = sc;
    atomicMax(&mkey[h], fkey(sc));
}

__global__ void ui_pass1_kernel(const int* __restrict__ uu,
                                const int* __restrict__ ii,
                                const float* __restrict__ su,
                                const float* __restrict__ S, int E,
                                float* __restrict__ score,
                                unsigned int* __restrict__ mkey) {
    int e = blockIdx.x * blockDim.x + threadIdx.x;
    if (e >= E) return;
    int u = uu[e], i = ii[e];
    float sc = su[u] + S[(size_t)i * 10 + 9];
    score[e] = sc;
    atomicMax(&mkey[u], fkey(sc));
}

// shared by kg/ui: score[e] <- exp(score[e]-m[dst]); ssum[dst] += .
__global__ void pass2_kernel(const int* __restrict__ dst,
                             const unsigned int* __restrict__ mkey,
                             int E, float* __restrict__ score,
                             float* __restrict__ ssum) {
    int e = blockIdx.x * blockDim.x + threadIdx.x;
    if (e >= E) return;
    int d = dst[e];
    float ev = expf(score[e] - funkey(mkey[d]));
    score[e] = ev;
    atomicAdd(&ssum[d], ev);
}

// wave per edge, lane per channel: agg[head] += E[tail]*rel*attn
__global__ void kg_pass3_kernel(const int* __restrict__ head,
                                const int* __restrict__ tail,
                                const int* __restrict__ etype,
                                const float* __restrict__ Eemb,
                                const float* __restrict__ relemb,
                                const float* __restrict__ score,
                                const float* __restrict__ ssum, int E,
                                float* __restrict__ agg) {
    int wid = blockIdx.x * 4 + (threadIdx.x >> 6);
    int lane = threadIdx.x & 63;
    if (wid >= E) return;
    int h = head[wid], t = tail[wid], r = etype[wid] - 1;
    float attn = score[wid] / (ssum[h] + 1e-16f);
    float v = Eemb[(size_t)t * 64 + lane] * relemb[r * 64 + lane] * attn;
    atomicAdd(&agg[(size_t)h * 64 + lane], v);
}

// wave per edge: uagg[u] += E[i]*w_e*attn
__global__ void ui_pass3_kernel(const int* __restrict__ uu,
                                const int* __restrict__ ii,
                                const float* __restrict__ Eemb,
                                const float* __restrict__ iw,
                                const float* __restrict__ score,
                                const float* __restrict__ ssum, int E,
                                float* __restrict__ uagg) {
    int wid = blockIdx.x * 4 + (threadIdx.x >> 6);
    int lane = threadIdx.x & 63;
    if (wid >= E) return;
    int u = uu[wid], i = ii[wid];
    float attn = score[wid] / (ssum[u] + 1e-16f);
    float v = Eemb[(size_t)i * 64 + lane] * iw[wid] * attn;
    atomicAdd(&uagg[(size_t)u * 64 + lane], v);
}

// in-place L2 normalize rows of agg; res += normalized
__global__ void norm_acc_kernel(float* __restrict__ agg, int n,
                                float* __restrict__ res) {
    int row = blockIdx.x * 4 + (threadIdx.x >> 6);
    int lane = threadIdx.x & 63;
    if (row >= n) return;
    size_t idx = (size_t)row * 64 + lane;
    float x = agg[idx];
    float ss = waveSum(x * x);
    float y = x / fmaxf(sqrtf(ss), 1e-12f);
    agg[idx] = y;
    res[idx] += y;
}

// ---------- launch ----------

extern "C" void kernel_launch(void* const* d_in, const int* in_sizes, int n_in,
                              void* d_out, int out_size, void* d_ws, size_t ws_size,
                              hipStream_t stream) {
    const float* user_emb   = (const float*)d_in[0];
    const float* entity_emb = (const float*)d_in[1];
    const int*   edge_index = (const int*)d_in[2];
    const int*   edge_type  = (const int*)d_in[3];
    const int*   inter_edge = (const int*)d_in[4];
    const float* inter_w    = (const float*)d_in[5];
    const float* relemb     = (const float*)d_in[6];
    const float* WQ         = (const float*)d_in[7];
    const float* WUI        = (const float*)d_in[8];

    const int C = 64;
    const int n_usr = in_sizes[0] / C;
    const int n_ent = in_sizes[1] / C;
    const int Ekg   = in_sizes[3];
    const int Eui   = in_sizes[5];
    const int* head = edge_index;
    const int* tail = edge_index + Ekg;
    const int* uu   = inter_edge;
    const int* ii   = inter_edge + Eui;

    float* ws = (float*)d_ws;
    float* w_all = ws;                         ws += 640;
    float* S     = ws;                         ws += (size_t)n_ent * 10;
    float* su    = ws;                         ws += n_usr;
    float* s_ent = ws;                         ws += n_ent;   // zero region start
    float* s_usr = ws;                         ws += n_usr;
    unsigned int* mk_ent = (unsigned int*)ws;  ws += n_ent;
    unsigned int* mk_usr = (unsigned int*)ws;  ws += n_usr;   // zero region end
    float* sc_kg = ws;                         ws += Ekg;
    float* sc_ui = ws;                         ws += Eui;
    float* eaggA = ws;                         ws += (size_t)n_ent * C;
    float* uaggA = ws;                         ws += (size_t)n_usr * C;
    float* eaggB = ws;                         ws += (size_t)n_ent * C;
    float* uaggB = ws;                         ws += (size_t)n_usr * C;

    float* out_ent = (float*)d_out;
    float* out_usr = out_ent + (size_t)n_ent * C;

    // residual init: res = initial embeddings
    hipMemcpyAsync(out_ent, entity_emb, (size_t)n_ent * C * sizeof(float),
                   hipMemcpyDeviceToDevice, stream);
    hipMemcpyAsync(out_usr, user_emb, (size_t)n_usr * C * sizeof(float),
                   hipMemcpyDeviceToDevice, stream);

    compute_w_kernel<<<1, 64, 0, stream>>>(WQ, WUI, relemb, edge_type, Ekg, w_all);

    const float* Ein = entity_emb;
    const float* Uin = user_emb;
    for (int hop = 0; hop < 2; ++hop) {
        float* eagg = (hop == 0) ? eaggA : eaggB;
        float* uagg = (hop == 0) ? uaggA : uaggB;

        // zero per-segment max/sum and the agg buffers for this hop
        hipMemsetAsync(s_ent, 0, (size_t)(n_ent + n_usr) * 2 * sizeof(float), stream);
        hipMemsetAsync(eagg, 0, (size_t)(n_ent + n_usr) * C * sizeof(float), stream);

        entity_tables_kernel<<<(n_ent + 3) / 4, 256, 0, stream>>>(Ein, n_ent, w_all, S);
        user_table_kernel<<<(n_usr + 3) / 4, 256, 0, stream>>>(Uin, n_usr, w_all, su);

        kg_pass1_kernel<<<(Ekg + 255) / 256, 256, 0, stream>>>(
            head, tail, edge_type, S, Ekg, sc_kg, mk_ent);
        ui_pass1_kernel<<<(Eui + 255) / 256, 256, 0, stream>>>(
            uu, ii, su, S, Eui, sc_ui, mk_usr);

        pass2_kernel<<<(Ekg + 255) / 256, 256, 0, stream>>>(head, mk_ent, Ekg, sc_kg, s_ent);
        pass2_kernel<<<(Eui + 255) / 256, 256, 0, stream>>>(uu, mk_usr, Eui, sc_ui, s_usr);

        kg_pass3_kernel<<<(Ekg + 3) / 4, 256, 0, stream>>>(
            head, tail, edge_type, Ein, relemb, sc_kg, s_ent, Ekg, eagg);
        ui_pass3_kernel<<<(Eui + 3) / 4, 256, 0, stream>>>(
            uu, ii, Ein, inter_w, sc_ui, s_usr, Eui, uagg);

        norm_acc_kernel<<<(n_ent + 3) / 4, 256, 0, stream>>>(eagg, n_ent, out_ent);
        norm_acc_kernel<<<(n_usr + 3) / 4, 256, 0, stream>>>(uagg, n_usr, out_usr);

        Ein = eagg;  // normalized in place -> next hop's entity_emb
        Uin = uagg;  // normalized in place -> next hop's user_emb
    }
}

// Round 2
// 1451.451 us; speedup vs baseline: 1.1215x; 1.1215x over previous
//
#include <hip/hip_runtime.h>

// ---------- helpers ----------

__device__ __forceinline__ float waveSum(float v) {
#pragma unroll
    for (int off = 32; off > 0; off >>= 1)
        v += __shfl_xor(v, off, 64);
    return v;
}

__device__ __forceinline__ float waveMax(float v) {
#pragma unroll
    for (int off = 32; off > 0; off >>= 1)
        v = fmaxf(v, __shfl_xor(v, off, 64));
    return v;
}

// ---------- setup kernels ----------

// w_all[r][k] = sum_c W_Q[k][c] * relemb[r][c]  for r=0..8 (edge_type-1)
// w_all[9][k] = sum_c W_UI[k][c] * relemb[edge_type[E-1]-1][c]   (rel_last)
__global__ void compute_w_kernel(const float* __restrict__ WQ,
                                 const float* __restrict__ WUI,
                                 const float* __restrict__ relemb,
                                 const int* __restrict__ etype, int Ekg,
                                 float* __restrict__ w_all) {
    int k = threadIdx.x; // 0..63
    for (int r = 0; r < 9; ++r) {
        float acc = 0.f;
#pragma unroll
        for (int c = 0; c < 64; ++c)
            acc = fmaf(WQ[k * 64 + c], relemb[r * 64 + c], acc);
        w_all[r * 64 + k] = acc;
    }
    int rl = etype[Ekg - 1] - 1;
    float acc = 0.f;
#pragma unroll
    for (int c = 0; c < 64; ++c)
        acc = fmaf(WUI[k * 64 + c], relemb[rl * 64 + c], acc);
    w_all[9 * 64 + k] = acc;
}

// S[i*10 + r] = E[i] . w_all[r]   (r=0..8 KG relations, r=9 -> UI key table)
__global__ void entity_tables_kernel(const float* __restrict__ E, int n_ent,
                                     const float* __restrict__ w_all,
                                     float* __restrict__ S) {
    __shared__ float w[640];
    for (int i = threadIdx.x; i < 640; i += blockDim.x) w[i] = w_all[i];
    __syncthreads();
    int wid = blockIdx.x * 4 + (threadIdx.x >> 6);
    int lane = threadIdx.x & 63;
    if (wid >= n_ent) return;
    float e = E[(size_t)wid * 64 + lane];
    float d[10];
#pragma unroll
    for (int r = 0; r < 10; ++r)
        d[r] = waveSum(e * w[r * 64 + lane]);
    if (lane == 0) {
#pragma unroll
        for (int r = 0; r < 10; ++r)
            S[(size_t)wid * 10 + r] = d[r];
    }
}

// su[u] = U[u] . w_all[9]
__global__ void user_table_kernel(const float* __restrict__ U, int n_usr,
                                  const float* __restrict__ w_all,
                                  float* __restrict__ su) {
    __shared__ float w[64];
    if (threadIdx.x < 64) w[threadIdx.x] = w_all[9 * 64 + threadIdx.x];
    __syncthreads();
    int wid = blockIdx.x * 4 + (threadIdx.x >> 6);
    int lane = threadIdx.x & 63;
    if (wid >= n_usr) return;
    float v = waveSum(U[(size_t)wid * 64 + lane] * w[lane]);
    if (lane == 0) su[wid] = v;
}

// ---------- CSR build ----------

__global__ void hist_kernel(const int* __restrict__ idx, int E,
                            unsigned int* __restrict__ deg) {
    int e = blockIdx.x * blockDim.x + threadIdx.x;
    if (e < E) atomicAdd(&deg[idx[e]], 1u);
}

// single-block inclusive scan -> exclusive offsets (off[0]=0, off[i+1]=incl[i])
__global__ void scan_kernel(const unsigned int* __restrict__ deg, int n,
                            unsigned int* __restrict__ off) {
    __shared__ unsigned int tmp[1024];
    __shared__ unsigned int carry;
    if (threadIdx.x == 0) carry = 0;
    __syncthreads();
    for (int base = 0; base < n; base += 1024) {
        int i = base + threadIdx.x;
        unsigned int v = (i < n) ? deg[i] : 0u;
        tmp[threadIdx.x] = v;
        __syncthreads();
        for (int s = 1; s < 1024; s <<= 1) {
            unsigned int add = (threadIdx.x >= (unsigned)s) ? tmp[threadIdx.x - s] : 0u;
            __syncthreads();
            tmp[threadIdx.x] += add;
            __syncthreads();
        }
        unsigned int inc = tmp[threadIdx.x] + carry;
        if (i < n) off[i + 1] = inc;
        __syncthreads();
        if (threadIdx.x == 1023) carry = inc;
        __syncthreads();
    }
    if (threadIdx.x == 0) off[0] = 0;
}

__global__ void kg_scatter_kernel(const int* __restrict__ head,
                                  const int* __restrict__ tail,
                                  const int* __restrict__ etype, int E,
                                  const unsigned int* __restrict__ off,
                                  unsigned int* __restrict__ cur,
                                  unsigned int* __restrict__ packed) {
    int e = blockIdx.x * blockDim.x + threadIdx.x;
    if (e >= E) return;
    int h = head[e];
    unsigned int pos = off[h] + atomicAdd(&cur[h], 1u);
    packed[pos] = (unsigned int)tail[e] | (((unsigned int)(etype[e] - 1)) << 20);
}

__global__ void ui_scatter_kernel(const int* __restrict__ uu,
                                  const int* __restrict__ ii,
                                  const float* __restrict__ iw, int E,
                                  const unsigned int* __restrict__ off,
                                  unsigned int* __restrict__ cur,
                                  unsigned int* __restrict__ sorted_i,
                                  float* __restrict__ sorted_w) {
    int e = blockIdx.x * blockDim.x + threadIdx.x;
    if (e >= E) return;
    int u = uu[e];
    unsigned int pos = off[u] + atomicAdd(&cur[u], 1u);
    sorted_i[pos] = (unsigned int)ii[e];
    sorted_w[pos] = iw[e];
}

// ---------- fused per-destination aggregation ----------

// wave per head entity: softmax over its CSR segment, weighted sum of
// E[tail]*rel rows, L2-normalize, write next-hop input + residual.
__global__ void kg_fused_kernel(const unsigned int* __restrict__ off,
                                const unsigned int* __restrict__ packed,
                                const float* __restrict__ S,
                                const float* __restrict__ Eemb,
                                const float* __restrict__ relemb,
                                int n_ent,
                                float* __restrict__ eagg,
                                float* __restrict__ res) {
    int h = blockIdx.x * 4 + (threadIdx.x >> 6);
    int lane = threadIdx.x & 63;
    if (h >= n_ent) return;
    unsigned int s0 = off[h], s1 = off[h + 1];

    // lane-parallel max
    float mloc = -INFINITY;
    for (unsigned int e = s0 + lane; e < s1; e += 64) {
        unsigned int te = packed[e];
        int t = te & 0xFFFFF, r = te >> 20;
        float sc = S[(size_t)h * 10 + r] + S[(size_t)t * 10 + r];
        mloc = fmaxf(mloc, sc);
    }
    float m = waveMax(mloc);

    // serial accumulate (lane = channel)
    float sum = 0.f, acc = 0.f;
    for (unsigned int e = s0; e < s1; ++e) {
        unsigned int te = packed[e];
        int t = te & 0xFFFFF, r = te >> 20;
        float sc = S[(size_t)h * 10 + r] + S[(size_t)t * 10 + r];
        float w = expf(sc - m);
        sum += w;
        acc = fmaf(w, Eemb[(size_t)t * 64 + lane] * relemb[r * 64 + lane], acc);
    }
    float y = acc / (sum + 1e-16f);
    float ss = waveSum(y * y);
    y = y / fmaxf(sqrtf(ss), 1e-12f);
    size_t idx = (size_t)h * 64 + lane;
    eagg[idx] = y;
    res[idx] += y;
}

// wave per user: same structure over UI edges.
__global__ void ui_fused_kernel(const unsigned int* __restrict__ off,
                                const unsigned int* __restrict__ sorted_i,
                                const float* __restrict__ sorted_w,
                                const float* __restrict__ su,
                                const float* __restrict__ S,
                                const float* __restrict__ Eemb,
                                int n_usr,
                                float* __restrict__ uagg,
                                float* __restrict__ res) {
    int u = blockIdx.x * 4 + (threadIdx.x >> 6);
    int lane = threadIdx.x & 63;
    if (u >= n_usr) return;
    unsigned int s0 = off[u], s1 = off[u + 1];
    float squ = su[u];

    float mloc = -INFINITY;
    for (unsigned int e = s0 + lane; e < s1; e += 64) {
        float sc = squ + S[(size_t)sorted_i[e] * 10 + 9];
        mloc = fmaxf(mloc, sc);
    }
    float m = waveMax(mloc);

    float sum = 0.f, acc = 0.f;
    for (unsigned int e = s0; e < s1; ++e) {
        unsigned int i = sorted_i[e];
        float sc = squ + S[(size_t)i * 10 + 9];
        float w = expf(sc - m);
        sum += w;
        acc = fmaf(w * sorted_w[e], Eemb[(size_t)i * 64 + lane], acc);
    }
    float y = acc / (sum + 1e-16f);
    float ss = waveSum(y * y);
    y = y / fmaxf(sqrtf(ss), 1e-12f);
    size_t idx = (size_t)u * 64 + lane;
    uagg[idx] = y;
    res[idx] += y;
}

// ---------- launch ----------

extern "C" void kernel_launch(void* const* d_in, const int* in_sizes, int n_in,
                              void* d_out, int out_size, void* d_ws, size_t ws_size,
                              hipStream_t stream) {
    const float* user_emb   = (const float*)d_in[0];
    const float* entity_emb = (const float*)d_in[1];
    const int*   edge_index = (const int*)d_in[2];
    const int*   edge_type  = (const int*)d_in[3];
    const int*   inter_edge = (const int*)d_in[4];
    const float* inter_w    = (const float*)d_in[5];
    const float* relemb     = (const float*)d_in[6];
    const float* WQ         = (const float*)d_in[7];
    const float* WUI        = (const float*)d_in[8];

    const int C = 64;
    const int n_usr = in_sizes[0] / C;
    const int n_ent = in_sizes[1] / C;
    const int Ekg   = in_sizes[3];
    const int Eui   = in_sizes[5];
    const int* head = edge_index;
    const int* tail = edge_index + Ekg;
    const int* uu   = inter_edge;
    const int* ii   = inter_edge + Eui;

    float* ws = (float*)d_ws;
    float* w_all = ws;                          ws += 640;
    float* S     = ws;                          ws += (size_t)n_ent * 10;
    float* su    = ws;                          ws += n_usr;
    unsigned int* deg_ent = (unsigned int*)ws;  ws += n_ent;   // also cursor
    unsigned int* deg_usr = (unsigned int*)ws;  ws += n_usr;   // also cursor
    unsigned int* off_ent = (unsigned int*)ws;  ws += n_ent + 1;
    unsigned int* off_usr = (unsigned int*)ws;  ws += n_usr + 1;
    unsigned int* packed  = (unsigned int*)ws;  ws += Ekg;
    unsigned int* sorted_i = (unsigned int*)ws; ws += Eui;
    float* sorted_w = ws;                       ws += Eui;
    float* eaggA = ws;                          ws += (size_t)n_ent * C;
    float* uaggA = ws;                          ws += (size_t)n_usr * C;
    float* eaggB = ws;                          ws += (size_t)n_ent * C;
    float* uaggB = ws;                          ws += (size_t)n_usr * C;

    float* out_ent = (float*)d_out;
    float* out_usr = out_ent + (size_t)n_ent * C;

    // residual init: res = initial embeddings
    hipMemcpyAsync(out_ent, entity_emb, (size_t)n_ent * C * sizeof(float),
                   hipMemcpyDeviceToDevice, stream);
    hipMemcpyAsync(out_usr, user_emb, (size_t)n_usr * C * sizeof(float),
                   hipMemcpyDeviceToDevice, stream);

    compute_w_kernel<<<1, 64, 0, stream>>>(WQ, WUI, relemb, edge_type, Ekg, w_all);

    // ---- CSR build (edges static across hops) ----
    hipMemsetAsync(deg_ent, 0, (size_t)(n_ent + n_usr) * sizeof(unsigned int), stream);
    hist_kernel<<<(Ekg + 255) / 256, 256, 0, stream>>>(head, Ekg, deg_ent);
    hist_kernel<<<(Eui + 255) / 256, 256, 0, stream>>>(uu, Eui, deg_usr);
    scan_kernel<<<1, 1024, 0, stream>>>(deg_ent, n_ent, off_ent);
    scan_kernel<<<1, 1024, 0, stream>>>(deg_usr, n_usr, off_usr);
    hipMemsetAsync(deg_ent, 0, (size_t)(n_ent + n_usr) * sizeof(unsigned int), stream);
    kg_scatter_kernel<<<(Ekg + 255) / 256, 256, 0, stream>>>(
        head, tail, edge_type, Ekg, off_ent, deg_ent, packed);
    ui_scatter_kernel<<<(Eui + 255) / 256, 256, 0, stream>>>(
        uu, ii, inter_w, Eui, off_usr, deg_usr, sorted_i, sorted_w);

    // ---- 2 hops, fully fused per-destination aggregation ----
    const float* Ein = entity_emb;
    const float* Uin = user_emb;
    for (int hop = 0; hop < 2; ++hop) {
        float* eagg = (hop == 0) ? eaggA : eaggB;
        float* uagg = (hop == 0) ? uaggA : uaggB;

        entity_tables_kernel<<<(n_ent + 3) / 4, 256, 0, stream>>>(Ein, n_ent, w_all, S);
        user_table_kernel<<<(n_usr + 3) / 4, 256, 0, stream>>>(Uin, n_usr, w_all, su);

        kg_fused_kernel<<<(n_ent + 3) / 4, 256, 0, stream>>>(
            off_ent, packed, S, Ein, relemb, n_ent, eagg, out_ent);
        ui_fused_kernel<<<(n_usr + 3) / 4, 256, 0, stream>>>(
            off_usr, sorted_i, sorted_w, su, S, Ein, n_usr, uagg, out_usr);

        Ein = eagg;
        Uin = uagg;
    }
}

// Round 4
// 1008.092 us; speedup vs baseline: 1.6147x; 1.4398x over previous
//
#include <hip/hip_runtime.h>

// ---------- helpers ----------

__device__ __forceinline__ float waveSum(float v) {
#pragma unroll
    for (int off = 32; off > 0; off >>= 1)
        v += __shfl_xor(v, off, 64);
    return v;
}

__device__ __forceinline__ float waveMax(float v) {
#pragma unroll
    for (int off = 32; off > 0; off >>= 1)
        v = fmaxf(v, __shfl_xor(v, off, 64));
    return v;
}

// ---------- setup kernels ----------

// w_all[r][k] = sum_c W_Q[k][c] * relemb[r][c]  for r=0..8 (edge_type-1)
// w_all[9][k] = sum_c W_UI[k][c] * relemb[edge_type[E-1]-1][c]   (rel_last)
__global__ void compute_w_kernel(const float* __restrict__ WQ,
                                 const float* __restrict__ WUI,
                                 const float* __restrict__ relemb,
                                 const int* __restrict__ etype, int Ekg,
                                 float* __restrict__ w_all) {
    int k = threadIdx.x; // 0..63
    for (int r = 0; r < 9; ++r) {
        float acc = 0.f;
#pragma unroll
        for (int c = 0; c < 64; ++c)
            acc = fmaf(WQ[k * 64 + c], relemb[r * 64 + c], acc);
        w_all[r * 64 + k] = acc;
    }
    int rl = etype[Ekg - 1] - 1;
    float acc = 0.f;
#pragma unroll
    for (int c = 0; c < 64; ++c)
        acc = fmaf(WUI[k * 64 + c], relemb[rl * 64 + c], acc);
    w_all[9 * 64 + k] = acc;
}

// S[i*10 + r] = E[i] . w_all[r]   (r=0..8 KG relations, r=9 -> UI key table)
__global__ void entity_tables_kernel(const float* __restrict__ E, int n_ent,
                                     const float* __restrict__ w_all,
                                     float* __restrict__ S) {
    __shared__ float w[640];
    for (int i = threadIdx.x; i < 640; i += blockDim.x) w[i] = w_all[i];
    __syncthreads();
    int wid = blockIdx.x * 4 + (threadIdx.x >> 6);
    int lane = threadIdx.x & 63;
    if (wid >= n_ent) return;
    float e = E[(size_t)wid * 64 + lane];
    float d[10];
#pragma unroll
    for (int r = 0; r < 10; ++r)
        d[r] = waveSum(e * w[r * 64 + lane]);
    if (lane == 0) {
#pragma unroll
        for (int r = 0; r < 10; ++r)
            S[(size_t)wid * 10 + r] = d[r];
    }
}

// su[u] = U[u] . w_all[9]
__global__ void user_table_kernel(const float* __restrict__ U, int n_usr,
                                  const float* __restrict__ w_all,
                                  float* __restrict__ su) {
    __shared__ float w[64];
    if (threadIdx.x < 64) w[threadIdx.x] = w_all[9 * 64 + threadIdx.x];
    __syncthreads();
    int wid = blockIdx.x * 4 + (threadIdx.x >> 6);
    int lane = threadIdx.x & 63;
    if (wid >= n_usr) return;
    float v = waveSum(U[(size_t)wid * 64 + lane] * w[lane]);
    if (lane == 0) su[wid] = v;
}

// ---------- CSR build ----------

__global__ void hist_kernel(const int* __restrict__ idx, int E,
                            unsigned int* __restrict__ deg) {
    int e = blockIdx.x * blockDim.x + threadIdx.x;
    if (e < E) atomicAdd(&deg[idx[e]], 1u);
}

// multi-block scan: CHUNK = 2048 elements per 256-thread block
#define SCAN_CHUNK 2048

__global__ void scan_pass1(const unsigned int* __restrict__ deg, int n,
                           unsigned int* __restrict__ bsums) {
    int base = blockIdx.x * SCAN_CHUNK;
    int tid = threadIdx.x;
    unsigned int s = 0;
#pragma unroll
    for (int j = 0; j < 8; ++j) {
        int i = base + tid * 8 + j;
        if (i < n) s += deg[i];
    }
    // wave reduce (uint)
#pragma unroll
    for (int off = 32; off > 0; off >>= 1)
        s += __shfl_xor(s, off, 64);
    __shared__ unsigned int wsm[4];
    if ((tid & 63) == 0) wsm[tid >> 6] = s;
    __syncthreads();
    if (tid == 0) bsums[blockIdx.x] = wsm[0] + wsm[1] + wsm[2] + wsm[3];
}

// single block: bsums -> exclusive prefix (nb <= 1024)
__global__ void scan_pass2(unsigned int* __restrict__ bsums, int nb) {
    __shared__ unsigned int tmp[1024];
    int tid = threadIdx.x;
    unsigned int v = (tid < nb) ? bsums[tid] : 0u;
    tmp[tid] = v;
    __syncthreads();
    for (int s = 1; s < 1024; s <<= 1) {
        unsigned int add = (tid >= s) ? tmp[tid - s] : 0u;
        __syncthreads();
        tmp[tid] += add;
        __syncthreads();
    }
    if (tid < nb) bsums[tid] = tmp[tid] - v; // exclusive
}

__global__ void scan_pass3(const unsigned int* __restrict__ deg, int n,
                           const unsigned int* __restrict__ bsums,
                           unsigned int* __restrict__ off) {
    int base = blockIdx.x * SCAN_CHUNK;
    int tid = threadIdx.x;
    int lane = tid & 63, wv = tid >> 6;
    unsigned int x[8];
    unsigned int s = 0;
#pragma unroll
    for (int j = 0; j < 8; ++j) {
        int i = base + tid * 8 + j;
        x[j] = (i < n) ? deg[i] : 0u;
        s += x[j];
    }
    // inclusive wave scan of per-thread totals
    unsigned int sc = s;
#pragma unroll
    for (int o = 1; o < 64; o <<= 1) {
        unsigned int t = __shfl_up(sc, o, 64);
        if (lane >= o) sc += t;
    }
    __shared__ unsigned int wtot[4];
    if (lane == 63) wtot[wv] = sc;
    __syncthreads();
    unsigned int woff = 0;
    for (int w = 0; w < wv; ++w) woff += wtot[w];
    unsigned int run = bsums[blockIdx.x] + woff + (sc - s); // exclusive before first elem
#pragma unroll
    for (int j = 0; j < 8; ++j) {
        int i = base + tid * 8 + j;
        run += x[j];
        if (i < n) off[i + 1] = run; // inclusive at i
    }
    if (blockIdx.x == 0 && tid == 0) off[0] = 0;
}

__global__ void kg_scatter_kernel(const int* __restrict__ head,
                                  const int* __restrict__ tail,
                                  const int* __restrict__ etype, int E,
                                  const unsigned int* __restrict__ off,
                                  unsigned int* __restrict__ cur,
                                  unsigned int* __restrict__ packed) {
    int e = blockIdx.x * blockDim.x + threadIdx.x;
    if (e >= E) return;
    int h = head[e];
    unsigned int pos = off[h] + atomicAdd(&cur[h], 1u);
    packed[pos] = (unsigned int)tail[e] | (((unsigned int)(etype[e] - 1)) << 20);
}

__global__ void ui_scatter_kernel(const int* __restrict__ uu,
                                  const int* __restrict__ ii,
                                  const float* __restrict__ iw, int E,
                                  const unsigned int* __restrict__ off,
                                  unsigned int* __restrict__ cur,
                                  unsigned int* __restrict__ sorted_i,
                                  float* __restrict__ sorted_w) {
    int e = blockIdx.x * blockDim.x + threadIdx.x;
    if (e >= E) return;
    int u = uu[e];
    unsigned int pos = off[u] + atomicAdd(&cur[u], 1u);
    sorted_i[pos] = (unsigned int)ii[e];
    sorted_w[pos] = iw[e];
}

// ---------- fused per-destination aggregation ----------

// wave per head entity: softmax over CSR segment, weighted sum of E[tail]*rel,
// L2-normalize, write next-hop input + residual (+ optional next-hop S table).
__global__ void kg_fused_kernel(const unsigned int* __restrict__ off,
                                const unsigned int* __restrict__ packed,
                                const float* __restrict__ S,
                                const float* __restrict__ Eemb,
                                const float* __restrict__ relemb,
                                const float* __restrict__ w_all,
                                int n_ent,
                                float* __restrict__ eagg,
                                float* __restrict__ Snext,
                                float* __restrict__ res,
                                const float* __restrict__ res_init) {
    __shared__ float w[640];
    __shared__ float rel[576];
    for (int i = threadIdx.x; i < 640; i += blockDim.x) w[i] = w_all[i];
    for (int i = threadIdx.x; i < 576; i += blockDim.x) rel[i] = relemb[i];
    __syncthreads();
    int h = blockIdx.x * 4 + (threadIdx.x >> 6);
    int lane = threadIdx.x & 63;
    if (h >= n_ent) return;
    unsigned int s0 = off[h], s1 = off[h + 1];

    float sh = (lane < 10) ? S[(size_t)h * 10 + lane] : 0.f;

    // lane-parallel max
    float mloc = -INFINITY;
    for (unsigned int e = s0 + lane; e < s1; e += 64) {
        unsigned int te = packed[e];
        int t = te & 0xFFFFF, r = te >> 20;
        float sc = __shfl(sh, r, 64) + S[(size_t)t * 10 + r];
        mloc = fmaxf(mloc, sc);
    }
    float m = waveMax(mloc);

    // serial accumulate (lane = channel)
    float sum = 0.f, acc = 0.f;
    for (unsigned int e = s0; e < s1; ++e) {
        unsigned int te = packed[e];
        int t = te & 0xFFFFF, r = te >> 20;
        float sc = __shfl(sh, r, 64) + S[(size_t)t * 10 + r];
        float wg = expf(sc - m);
        sum += wg;
        acc = fmaf(wg, Eemb[(size_t)t * 64 + lane] * rel[r * 64 + lane], acc);
    }
    float y = acc / (sum + 1e-16f);
    float ss = waveSum(y * y);
    y = y / fmaxf(sqrtf(ss), 1e-12f);
    size_t idx = (size_t)h * 64 + lane;
    eagg[idx] = y;
    if (res_init) res[idx] = res_init[idx] + y;
    else          res[idx] += y;
    if (Snext) {
        float d[10];
#pragma unroll
        for (int r = 0; r < 10; ++r)
            d[r] = waveSum(y * w[r * 64 + lane]);
        if (lane == 0) {
#pragma unroll
            for (int r = 0; r < 10; ++r)
                Snext[(size_t)h * 10 + r] = d[r];
        }
    }
}

// wave per user: same structure over UI edges (+ optional next-hop su).
__global__ void ui_fused_kernel(const unsigned int* __restrict__ off,
                                const unsigned int* __restrict__ sorted_i,
                                const float* __restrict__ sorted_w,
                                const float* __restrict__ su,
                                const float* __restrict__ S,
                                const float* __restrict__ Eemb,
                                const float* __restrict__ w_all,
                                int n_usr,
                                float* __restrict__ uagg,
                                float* __restrict__ sunext,
                                float* __restrict__ res,
                                const float* __restrict__ res_init) {
    __shared__ float w9[64];
    if (threadIdx.x < 64) w9[threadIdx.x] = w_all[9 * 64 + threadIdx.x];
    __syncthreads();
    int u = blockIdx.x * 4 + (threadIdx.x >> 6);
    int lane = threadIdx.x & 63;
    if (u >= n_usr) return;
    unsigned int s0 = off[u], s1 = off[u + 1];
    float squ = su[u];

    float mloc = -INFINITY;
    for (unsigned int e = s0 + lane; e < s1; e += 64) {
        float sc = squ + S[(size_t)sorted_i[e] * 10 + 9];
        mloc = fmaxf(mloc, sc);
    }
    float m = waveMax(mloc);

    float sum = 0.f, acc = 0.f;
    for (unsigned int e = s0; e < s1; ++e) {
        unsigned int i = sorted_i[e];
        float sc = squ + S[(size_t)i * 10 + 9];
        float wg = expf(sc - m);
        sum += wg;
        acc = fmaf(wg * sorted_w[e], Eemb[(size_t)i * 64 + lane], acc);
    }
    float y = acc / (sum + 1e-16f);
    float ss = waveSum(y * y);
    y = y / fmaxf(sqrtf(ss), 1e-12f);
    size_t idx = (size_t)u * 64 + lane;
    uagg[idx] = y;
    if (res_init) res[idx] = res_init[idx] + y;
    else          res[idx] += y;
    if (sunext) {
        float v = waveSum(y * w9[lane]);
        if (lane == 0) sunext[u] = v;
    }
}

// ---------- launch ----------

extern "C" void kernel_launch(void* const* d_in, const int* in_sizes, int n_in,
                              void* d_out, int out_size, void* d_ws, size_t ws_size,
                              hipStream_t stream) {
    const float* user_emb   = (const float*)d_in[0];
    const float* entity_emb = (const float*)d_in[1];
    const int*   edge_index = (const int*)d_in[2];
    const int*   edge_type  = (const int*)d_in[3];
    const int*   inter_edge = (const int*)d_in[4];
    const float* inter_w    = (const float*)d_in[5];
    const float* relemb     = (const float*)d_in[6];
    const float* WQ         = (const float*)d_in[7];
    const float* WUI        = (const float*)d_in[8];

    const int C = 64;
    const int n_usr = in_sizes[0] / C;
    const int n_ent = in_sizes[1] / C;
    const int Ekg   = in_sizes[3];
    const int Eui   = in_sizes[5];
    const int* head = edge_index;
    const int* tail = edge_index + Ekg;
    const int* uu   = inter_edge;
    const int* ii   = inter_edge + Eui;

    float* ws = (float*)d_ws;
    float* w_all = ws;                          ws += 640;
    float* S0    = ws;                          ws += (size_t)n_ent * 10;
    float* S1    = ws;                          ws += (size_t)n_ent * 10;
    float* su0   = ws;                          ws += n_usr;
    float* su1   = ws;                          ws += n_usr;
    unsigned int* deg_ent = (unsigned int*)ws;  ws += n_ent;   // also cursor
    unsigned int* deg_usr = (unsigned int*)ws;  ws += n_usr;   // also cursor
    unsigned int* off_ent = (unsigned int*)ws;  ws += n_ent + 1;
    unsigned int* off_usr = (unsigned int*)ws;  ws += n_usr + 1;
    unsigned int* bsum_e  = (unsigned int*)ws;  ws += 1024;
    unsigned int* bsum_u  = (unsigned int*)ws;  ws += 1024;
    unsigned int* packed  = (unsigned int*)ws;  ws += Ekg;
    unsigned int* sorted_i = (unsigned int*)ws; ws += Eui;
    float* sorted_w = ws;                       ws += Eui;
    float* eaggA = ws;                          ws += (size_t)n_ent * C;
    float* uaggA = ws;                          ws += (size_t)n_usr * C;
    float* eaggB = ws;                          ws += (size_t)n_ent * C;
    float* uaggB = ws;                          ws += (size_t)n_usr * C;

    float* out_ent = (float*)d_out;
    float* out_usr = out_ent + (size_t)n_ent * C;

    compute_w_kernel<<<1, 64, 0, stream>>>(WQ, WUI, relemb, edge_type, Ekg, w_all);

    // ---- CSR build (edges static across hops) ----
    hipMemsetAsync(deg_ent, 0, (size_t)(n_ent + n_usr) * sizeof(unsigned int), stream);
    hist_kernel<<<(Ekg + 255) / 256, 256, 0, stream>>>(head, Ekg, deg_ent);
    hist_kernel<<<(Eui + 255) / 256, 256, 0, stream>>>(uu, Eui, deg_usr);

    int nb_e = (n_ent + SCAN_CHUNK - 1) / SCAN_CHUNK;
    int nb_u = (n_usr + SCAN_CHUNK - 1) / SCAN_CHUNK;
    scan_pass1<<<nb_e, 256, 0, stream>>>(deg_ent, n_ent, bsum_e);
    scan_pass2<<<1, 1024, 0, stream>>>(bsum_e, nb_e);
    scan_pass3<<<nb_e, 256, 0, stream>>>(deg_ent, n_ent, bsum_e, off_ent);
    scan_pass1<<<nb_u, 256, 0, stream>>>(deg_usr, n_usr, bsum_u);
    scan_pass2<<<1, 1024, 0, stream>>>(bsum_u, nb_u);
    scan_pass3<<<nb_u, 256, 0, stream>>>(deg_usr, n_usr, bsum_u, off_usr);

    hipMemsetAsync(deg_ent, 0, (size_t)(n_ent + n_usr) * sizeof(unsigned int), stream);
    kg_scatter_kernel<<<(Ekg + 255) / 256, 256, 0, stream>>>(
        head, tail, edge_type, Ekg, off_ent, deg_ent, packed);
    ui_scatter_kernel<<<(Eui + 255) / 256, 256, 0, stream>>>(
        uu, ii, inter_w, Eui, off_usr, deg_usr, sorted_i, sorted_w);

    // ---- hop-0 tables from original embeddings ----
    entity_tables_kernel<<<(n_ent + 3) / 4, 256, 0, stream>>>(entity_emb, n_ent, w_all, S0);
    user_table_kernel<<<(n_usr + 3) / 4, 256, 0, stream>>>(user_emb, n_usr, w_all, su0);

    // ---- hop 0: also emits S1/su1 for hop 1, and res = init + y ----
    kg_fused_kernel<<<(n_ent + 3) / 4, 256, 0, stream>>>(
        off_ent, packed, S0, entity_emb, relemb, w_all, n_ent,
        eaggA, S1, out_ent, entity_emb);
    ui_fused_kernel<<<(n_usr + 3) / 4, 256, 0, stream>>>(
        off_usr, sorted_i, sorted_w, su0, S0, entity_emb, w_all, n_usr,
        uaggA, su1, out_usr, user_emb);

    // ---- hop 1: res += y ----
    kg_fused_kernel<<<(n_ent + 3) / 4, 256, 0, stream>>>(
        off_ent, packed, S1, eaggA, relemb, w_all, n_ent,
        eaggB, nullptr, out_ent, nullptr);
    ui_fused_kernel<<<(n_usr + 3) / 4, 256, 0, stream>>>(
        off_usr, sorted_i, sorted_w, su1, S1, eaggA, w_all, n_usr,
        uaggB, nullptr, out_usr, nullptr);
}

// Round 5
// 625.170 us; speedup vs baseline: 2.6037x; 1.6125x over previous
//
#include <hip/hip_runtime.h>

// ---------- helpers ----------

__device__ __forceinline__ float waveSum(float v) {
#pragma unroll
    for (int off = 32; off > 0; off >>= 1)
        v += __shfl_xor(v, off, 64);
    return v;
}

__device__ __forceinline__ float waveMax(float v) {
#pragma unroll
    for (int off = 32; off > 0; off >>= 1)
        v = fmaxf(v, __shfl_xor(v, off, 64));
    return v;
}

__device__ __forceinline__ float red16(float p) {
    p += __shfl_xor(p, 1, 64);
    p += __shfl_xor(p, 2, 64);
    p += __shfl_xor(p, 4, 64);
    p += __shfl_xor(p, 8, 64);
    return p;
}

// ---------- setup kernels ----------

// w_all[r][k] = sum_c W_Q[k][c] * relemb[r][c]  for r=0..8 (edge_type-1)
// w_all[9][k] = sum_c W_UI[k][c] * relemb[edge_type[E-1]-1][c]   (rel_last)
__global__ void compute_w_kernel(const float* __restrict__ WQ,
                                 const float* __restrict__ WUI,
                                 const float* __restrict__ relemb,
                                 const int* __restrict__ etype, int Ekg,
                                 float* __restrict__ w_all) {
    int k = threadIdx.x; // 0..63
    for (int r = 0; r < 9; ++r) {
        float acc = 0.f;
#pragma unroll
        for (int c = 0; c < 64; ++c)
            acc = fmaf(WQ[k * 64 + c], relemb[r * 64 + c], acc);
        w_all[r * 64 + k] = acc;
    }
    int rl = etype[Ekg - 1] - 1;
    float acc = 0.f;
#pragma unroll
    for (int c = 0; c < 64; ++c)
        acc = fmaf(WUI[k * 64 + c], relemb[rl * 64 + c], acc);
    w_all[9 * 64 + k] = acc;
}

// S[i*10 + r] = E[i] . w_all[r]; 4 rows per wave, float4 lanes
__global__ void entity_tables_kernel(const float* __restrict__ E, int n_ent,
                                     const float* __restrict__ w_all,
                                     float* __restrict__ S) {
    __shared__ float4 w4[160];
    for (int i = threadIdx.x; i < 160; i += blockDim.x)
        w4[i] = ((const float4*)w_all)[i];
    __syncthreads();
    int wid = blockIdx.x * 4 + (threadIdx.x >> 6);
    int lane = threadIdx.x & 63;
    int grp = lane >> 4, l16 = lane & 15;
    int row = wid * 4 + grp;
    float4 ev = make_float4(0.f, 0.f, 0.f, 0.f);
    if (row < n_ent) ev = ((const float4*)E)[(size_t)row * 16 + l16];
#pragma unroll
    for (int r = 0; r < 10; ++r) {
        float4 wv = w4[r * 16 + l16];
        float p = ev.x * wv.x + ev.y * wv.y + ev.z * wv.z + ev.w * wv.w;
        p = red16(p);
        if (l16 == 0 && row < n_ent) S[(size_t)row * 10 + r] = p;
    }
}

// su[u] = U[u] . w_all[9]; 4 rows per wave
__global__ void user_table_kernel(const float* __restrict__ U, int n_usr,
                                  const float* __restrict__ w_all,
                                  float* __restrict__ su) {
    __shared__ float4 w9[16];
    if (threadIdx.x < 16) w9[threadIdx.x] = ((const float4*)w_all)[144 + threadIdx.x];
    __syncthreads();
    int wid = blockIdx.x * 4 + (threadIdx.x >> 6);
    int lane = threadIdx.x & 63;
    int grp = lane >> 4, l16 = lane & 15;
    int row = wid * 4 + grp;
    float4 ev = make_float4(0.f, 0.f, 0.f, 0.f);
    if (row < n_usr) ev = ((const float4*)U)[(size_t)row * 16 + l16];
    float4 wv = w9[l16];
    float p = ev.x * wv.x + ev.y * wv.y + ev.z * wv.z + ev.w * wv.w;
    p = red16(p);
    if (l16 == 0 && row < n_usr) su[row] = p;
}

// ---------- CSR build ----------

__global__ void hist_kernel(const int* __restrict__ idx, int E,
                            unsigned int* __restrict__ deg) {
    int e = blockIdx.x * blockDim.x + threadIdx.x;
    if (e < E) atomicAdd(&deg[idx[e]], 1u);
}

#define SCAN_CHUNK 2048

__global__ void scan_pass1(const unsigned int* __restrict__ deg, int n,
                           unsigned int* __restrict__ bsums) {
    int base = blockIdx.x * SCAN_CHUNK;
    int tid = threadIdx.x;
    unsigned int s = 0;
#pragma unroll
    for (int j = 0; j < 8; ++j) {
        int i = base + tid * 8 + j;
        if (i < n) s += deg[i];
    }
#pragma unroll
    for (int off = 32; off > 0; off >>= 1)
        s += __shfl_xor(s, off, 64);
    __shared__ unsigned int wsm[4];
    if ((tid & 63) == 0) wsm[tid >> 6] = s;
    __syncthreads();
    if (tid == 0) bsums[blockIdx.x] = wsm[0] + wsm[1] + wsm[2] + wsm[3];
}

__global__ void scan_pass2(unsigned int* __restrict__ bsums, int nb) {
    __shared__ unsigned int tmp[1024];
    int tid = threadIdx.x;
    unsigned int v = (tid < nb) ? bsums[tid] : 0u;
    tmp[tid] = v;
    __syncthreads();
    for (int s = 1; s < 1024; s <<= 1) {
        unsigned int add = (tid >= s) ? tmp[tid - s] : 0u;
        __syncthreads();
        tmp[tid] += add;
        __syncthreads();
    }
    if (tid < nb) bsums[tid] = tmp[tid] - v; // exclusive
}

__global__ void scan_pass3(const unsigned int* __restrict__ deg, int n,
                           const unsigned int* __restrict__ bsums,
                           unsigned int* __restrict__ off) {
    int base = blockIdx.x * SCAN_CHUNK;
    int tid = threadIdx.x;
    int lane = tid & 63, wv = tid >> 6;
    unsigned int x[8];
    unsigned int s = 0;
#pragma unroll
    for (int j = 0; j < 8; ++j) {
        int i = base + tid * 8 + j;
        x[j] = (i < n) ? deg[i] : 0u;
        s += x[j];
    }
    unsigned int sc = s;
#pragma unroll
    for (int o = 1; o < 64; o <<= 1) {
        unsigned int t = __shfl_up(sc, o, 64);
        if (lane >= o) sc += t;
    }
    __shared__ unsigned int wtot[4];
    if (lane == 63) wtot[wv] = sc;
    __syncthreads();
    unsigned int woff = 0;
    for (int w = 0; w < wv; ++w) woff += wtot[w];
    unsigned int run = bsums[blockIdx.x] + woff + (sc - s);
#pragma unroll
    for (int j = 0; j < 8; ++j) {
        int i = base + tid * 8 + j;
        run += x[j];
        if (i < n) off[i + 1] = run;
    }
    if (blockIdx.x == 0 && tid == 0) off[0] = 0;
}

__global__ void kg_scatter_kernel(const int* __restrict__ head,
                                  const int* __restrict__ tail,
                                  const int* __restrict__ etype, int E,
                                  const unsigned int* __restrict__ off,
                                  unsigned int* __restrict__ cur,
                                  unsigned int* __restrict__ packed) {
    int e = blockIdx.x * blockDim.x + threadIdx.x;
    if (e >= E) return;
    int h = head[e];
    unsigned int pos = off[h] + atomicAdd(&cur[h], 1u);
    packed[pos] = (unsigned int)tail[e] | (((unsigned int)(etype[e] - 1)) << 20);
}

__global__ void ui_scatter_kernel(const int* __restrict__ uu,
                                  const int* __restrict__ ii,
                                  const float* __restrict__ iw, int E,
                                  const unsigned int* __restrict__ off,
                                  unsigned int* __restrict__ cur,
                                  unsigned int* __restrict__ sorted_i,
                                  float* __restrict__ sorted_w) {
    int e = blockIdx.x * blockDim.x + threadIdx.x;
    if (e >= E) return;
    int u = uu[e];
    unsigned int pos = off[u] + atomicAdd(&cur[u], 1u);
    sorted_i[pos] = (unsigned int)ii[e];
    sorted_w[pos] = iw[e];
}

// ---------- fused per-destination aggregation (4-edge float4 gather) ----------

__global__ void kg_fused_kernel(const unsigned int* __restrict__ off,
                                const unsigned int* __restrict__ packed,
                                const float* __restrict__ S,
                                const float* __restrict__ Eemb,
                                const float* __restrict__ relemb,
                                const float* __restrict__ w_all,
                                int n_ent,
                                float* __restrict__ eagg,
                                float* __restrict__ Snext,
                                float* __restrict__ res,
                                const float* __restrict__ res_init) {
    __shared__ float4 rel4[144]; // 9 relations x 16 float4
    __shared__ float4 w4[160];   // 10 x 16 float4
    for (int i = threadIdx.x; i < 144; i += blockDim.x)
        rel4[i] = ((const float4*)relemb)[i];
    for (int i = threadIdx.x; i < 160; i += blockDim.x)
        w4[i] = ((const float4*)w_all)[i];
    __syncthreads();

    int h = blockIdx.x * 4 + (threadIdx.x >> 6);
    int lane = threadIdx.x & 63;
    if (h >= n_ent) return;
    int grp = lane >> 4, l16 = lane & 15;
    unsigned int s0 = off[h], s1 = off[h + 1];
    unsigned int cnt = s1 - s0;

    float sh = (lane < 10) ? S[(size_t)h * 10 + lane] : 0.f;

    // ---- pass A: segment max (score kept in regs when cnt<=64) ----
    float sc = -INFINITY;
    unsigned int pk = 0;
    float m;
    if (cnt <= 64) {
        bool v = lane < cnt;
        pk = v ? packed[s0 + lane] : 0u;
        int t = pk & 0xFFFFF, r = pk >> 20;
        float q = __shfl(sh, r, 64);
        if (v) sc = q + S[(size_t)t * 10 + r];
        m = waveMax(sc);
    } else {
        float ml = -INFINITY;
        for (unsigned int base = s0; base < s1; base += 64) {
            unsigned int e = base + lane;
            bool v = e < s1;
            unsigned int te = v ? packed[e] : 0u;
            int t = te & 0xFFFFF, r = te >> 20;
            float q = __shfl(sh, r, 64);
            if (v) ml = fmaxf(ml, q + S[(size_t)t * 10 + r]);
        }
        m = waveMax(ml);
    }

    // ---- pass B: exp weights + 4-edge float4 gather ----
    float4 acc = make_float4(0.f, 0.f, 0.f, 0.f);
    float wsum = 0.f;
    for (unsigned int base = s0; base < s1; base += 64) {
        unsigned int rem = s1 - base;
        unsigned int c = rem < 64u ? rem : 64u;
        float wg = 0.f;
        unsigned int te = 0u;
        if (cnt <= 64) {
            te = pk;
            if (lane < c) wg = expf(sc - m);
        } else {
            unsigned int e = base + lane;
            bool v = lane < c;
            te = v ? packed[e] : 0u;
            int t = te & 0xFFFFF, r = te >> 20;
            float q = __shfl(sh, r, 64);
            if (v) wg = expf(q + S[(size_t)t * 10 + r] - m);
        }
        wsum += wg;
        unsigned int jmax = (c + 3) >> 2;
        for (unsigned int j = 0; j < jmax; ++j) {
            unsigned int src = j * 4 + grp;
            bool v = src < c;
            int srcc = v ? (int)src : 0;
            float w_e = __shfl(wg, srcc, 64);
            unsigned int te_e = (unsigned int)__shfl((int)te, srcc, 64);
            if (v) {
                int t = te_e & 0xFFFFF, r = te_e >> 20;
                float4 evv = ((const float4*)(Eemb + (size_t)t * 64))[l16];
                float4 rv = rel4[r * 16 + l16];
                acc.x = fmaf(w_e, evv.x * rv.x, acc.x);
                acc.y = fmaf(w_e, evv.y * rv.y, acc.y);
                acc.z = fmaf(w_e, evv.z * rv.z, acc.z);
                acc.w = fmaf(w_e, evv.w * rv.w, acc.w);
            }
        }
    }
    float sum = waveSum(wsum);

    // cross-group butterfly: all lanes end with full channel sums
    acc.x += __shfl_xor(acc.x, 16, 64); acc.y += __shfl_xor(acc.y, 16, 64);
    acc.z += __shfl_xor(acc.z, 16, 64); acc.w += __shfl_xor(acc.w, 16, 64);
    acc.x += __shfl_xor(acc.x, 32, 64); acc.y += __shfl_xor(acc.y, 32, 64);
    acc.z += __shfl_xor(acc.z, 32, 64); acc.w += __shfl_xor(acc.w, 32, 64);

    float inv = 1.f / (sum + 1e-16f);
    float4 y = make_float4(acc.x * inv, acc.y * inv, acc.z * inv, acc.w * inv);
    float ss = y.x * y.x + y.y * y.y + y.z * y.z + y.w * y.w;
    ss = red16(ss);
    float sinv = 1.f / fmaxf(sqrtf(ss), 1e-12f);
    y.x *= sinv; y.y *= sinv; y.z *= sinv; y.w *= sinv;

    size_t rowoff = (size_t)h * 16 + l16;
    if (grp == 0) {
        ((float4*)eagg)[rowoff] = y;
        float4 o;
        if (res_init) {
            float4 ri = ((const float4*)res_init)[rowoff];
            o = make_float4(ri.x + y.x, ri.y + y.y, ri.z + y.z, ri.w + y.w);
        } else {
            float4 cur = ((const float4*)res)[rowoff];
            o = make_float4(cur.x + y.x, cur.y + y.y, cur.z + y.z, cur.w + y.w);
        }
        ((float4*)res)[rowoff] = o;
    }
    if (Snext) {
#pragma unroll
        for (int j = 0; j < 3; ++j) {
            int r = grp + 4 * j; // 0..11
            float p = 0.f;
            if (r < 10) {
                float4 wv = w4[r * 16 + l16];
                p = y.x * wv.x + y.y * wv.y + y.z * wv.z + y.w * wv.w;
            }
            p = red16(p);
            if (r < 10 && l16 == 0) Snext[(size_t)h * 10 + r] = p;
        }
    }
}

__global__ void ui_fused_kernel(const unsigned int* __restrict__ off,
                                const unsigned int* __restrict__ sorted_i,
                                const float* __restrict__ sorted_w,
                                const float* __restrict__ su,
                                const float* __restrict__ S,
                                const float* __restrict__ Eemb,
                                const float* __restrict__ w_all,
                                int n_usr,
                                float* __restrict__ uagg,
                                float* __restrict__ sunext,
                                float* __restrict__ res,
                                const float* __restrict__ res_init) {
    __shared__ float4 w9[16];
    if (threadIdx.x < 16) w9[threadIdx.x] = ((const float4*)w_all)[144 + threadIdx.x];
    __syncthreads();

    int u = blockIdx.x * 4 + (threadIdx.x >> 6);
    int lane = threadIdx.x & 63;
    if (u >= n_usr) return;
    int grp = lane >> 4, l16 = lane & 15;
    unsigned int s0 = off[u], s1 = off[u + 1];
    unsigned int cnt = s1 - s0;
    float squ = su[u];

    // ---- pass A ----
    float sc = -INFINITY;
    unsigned int ireg = 0; float swreg = 0.f;
    float m;
    if (cnt <= 64) {
        bool v = lane < cnt;
        if (v) {
            ireg = sorted_i[s0 + lane];
            swreg = sorted_w[s0 + lane];
            sc = squ + S[(size_t)ireg * 10 + 9];
        }
        m = waveMax(sc);
    } else {
        float ml = -INFINITY;
        for (unsigned int e = s0 + lane; e < s1; e += 64)
            ml = fmaxf(ml, squ + S[(size_t)sorted_i[e] * 10 + 9]);
        m = waveMax(ml);
    }

    // ---- pass B ----
    float4 acc = make_float4(0.f, 0.f, 0.f, 0.f);
    float wsum = 0.f;
    for (unsigned int base = s0; base < s1; base += 64) {
        unsigned int rem = s1 - base;
        unsigned int c = rem < 64u ? rem : 64u;
        float cw = 0.f, wg = 0.f;
        unsigned int ie = 0u;
        if (cnt <= 64) {
            ie = ireg;
            if (lane < c) { wg = expf(sc - m); cw = wg * swreg; }
        } else {
            unsigned int e = base + lane;
            bool v = lane < c;
            if (v) {
                ie = sorted_i[e];
                wg = expf(squ + S[(size_t)ie * 10 + 9] - m);
                cw = wg * sorted_w[e];
            }
        }
        wsum += wg;
        unsigned int jmax = (c + 3) >> 2;
        for (unsigned int j = 0; j < jmax; ++j) {
            unsigned int src = j * 4 + grp;
            bool v = src < c;
            int srcc = v ? (int)src : 0;
            float w_e = __shfl(cw, srcc, 64);
            unsigned int i_e = (unsigned int)__shfl((int)ie, srcc, 64);
            if (v) {
                float4 evv = ((const float4*)(Eemb + (size_t)i_e * 64))[l16];
                acc.x = fmaf(w_e, evv.x, acc.x);
                acc.y = fmaf(w_e, evv.y, acc.y);
                acc.z = fmaf(w_e, evv.z, acc.z);
                acc.w = fmaf(w_e, evv.w, acc.w);
            }
        }
    }
    float sum = waveSum(wsum);

    acc.x += __shfl_xor(acc.x, 16, 64); acc.y += __shfl_xor(acc.y, 16, 64);
    acc.z += __shfl_xor(acc.z, 16, 64); acc.w += __shfl_xor(acc.w, 16, 64);
    acc.x += __shfl_xor(acc.x, 32, 64); acc.y += __shfl_xor(acc.y, 32, 64);
    acc.z += __shfl_xor(acc.z, 32, 64); acc.w += __shfl_xor(acc.w, 32, 64);

    float inv = 1.f / (sum + 1e-16f);
    float4 y = make_float4(acc.x * inv, acc.y * inv, acc.z * inv, acc.w * inv);
    float ss = y.x * y.x + y.y * y.y + y.z * y.z + y.w * y.w;
    ss = red16(ss);
    float sinv = 1.f / fmaxf(sqrtf(ss), 1e-12f);
    y.x *= sinv; y.y *= sinv; y.z *= sinv; y.w *= sinv;

    size_t rowoff = (size_t)u * 16 + l16;
    if (grp == 0) {
        ((float4*)uagg)[rowoff] = y;
        float4 o;
        if (res_init) {
            float4 ri = ((const float4*)res_init)[rowoff];
            o = make_float4(ri.x + y.x, ri.y + y.y, ri.z + y.z, ri.w + y.w);
        } else {
            float4 cur = ((const float4*)res)[rowoff];
            o = make_float4(cur.x + y.x, cur.y + y.y, cur.z + y.z, cur.w + y.w);
        }
        ((float4*)res)[rowoff] = o;
    }
    if (sunext) {
        float4 wv = w9[l16];
        float p = y.x * wv.x + y.y * wv.y + y.z * wv.z + y.w * wv.w;
        p = red16(p);
        if (lane == 0) sunext[u] = p;
    }
}

// ---------- launch ----------

extern "C" void kernel_launch(void* const* d_in, const int* in_sizes, int n_in,
                              void* d_out, int out_size, void* d_ws, size_t ws_size,
                              hipStream_t stream) {
    const float* user_emb   = (const float*)d_in[0];
    const float* entity_emb = (const float*)d_in[1];
    const int*   edge_index = (const int*)d_in[2];
    const int*   edge_type  = (const int*)d_in[3];
    const int*   inter_edge = (const int*)d_in[4];
    const float* inter_w    = (const float*)d_in[5];
    const float* relemb     = (const float*)d_in[6];
    const float* WQ         = (const float*)d_in[7];
    const float* WUI        = (const float*)d_in[8];

    const int C = 64;
    const int n_usr = in_sizes[0] / C;
    const int n_ent = in_sizes[1] / C;
    const int Ekg   = in_sizes[3];
    const int Eui   = in_sizes[5];
    const int* head = edge_index;
    const int* tail = edge_index + Ekg;
    const int* uu   = inter_edge;
    const int* ii   = inter_edge + Eui;

    float* ws = (float*)d_ws;
    float* w_all = ws;                          ws += 640;
    float* S0    = ws;                          ws += (size_t)n_ent * 10;
    float* S1    = ws;                          ws += (size_t)n_ent * 10;
    float* su0   = ws;                          ws += n_usr;
    float* su1   = ws;                          ws += n_usr;
    unsigned int* deg_ent = (unsigned int*)ws;  ws += n_ent;   // also cursor
    unsigned int* deg_usr = (unsigned int*)ws;  ws += n_usr;   // also cursor
    unsigned int* off_ent = (unsigned int*)ws;  ws += n_ent + 1;
    unsigned int* off_usr = (unsigned int*)ws;  ws += n_usr + 1;
    unsigned int* bsum_e  = (unsigned int*)ws;  ws += 1024;
    unsigned int* bsum_u  = (unsigned int*)ws;  ws += 1024;
    unsigned int* packed  = (unsigned int*)ws;  ws += Ekg;
    unsigned int* sorted_i = (unsigned int*)ws; ws += Eui;
    float* sorted_w = ws;                       ws += Eui;
    float* eaggA = ws;                          ws += (size_t)n_ent * C;
    float* uaggA = ws;                          ws += (size_t)n_usr * C;
    float* eaggB = ws;                          ws += (size_t)n_ent * C;
    float* uaggB = ws;                          ws += (size_t)n_usr * C;

    float* out_ent = (float*)d_out;
    float* out_usr = out_ent + (size_t)n_ent * C;

    compute_w_kernel<<<1, 64, 0, stream>>>(WQ, WUI, relemb, edge_type, Ekg, w_all);

    // ---- CSR build (edges static across hops) ----
    hipMemsetAsync(deg_ent, 0, (size_t)(n_ent + n_usr) * sizeof(unsigned int), stream);
    hist_kernel<<<(Ekg + 255) / 256, 256, 0, stream>>>(head, Ekg, deg_ent);
    hist_kernel<<<(Eui + 255) / 256, 256, 0, stream>>>(uu, Eui, deg_usr);

    int nb_e = (n_ent + SCAN_CHUNK - 1) / SCAN_CHUNK;
    int nb_u = (n_usr + SCAN_CHUNK - 1) / SCAN_CHUNK;
    scan_pass1<<<nb_e, 256, 0, stream>>>(deg_ent, n_ent, bsum_e);
    scan_pass2<<<1, 1024, 0, stream>>>(bsum_e, nb_e);
    scan_pass3<<<nb_e, 256, 0, stream>>>(deg_ent, n_ent, bsum_e, off_ent);
    scan_pass1<<<nb_u, 256, 0, stream>>>(deg_usr, n_usr, bsum_u);
    scan_pass2<<<1, 1024, 0, stream>>>(bsum_u, nb_u);
    scan_pass3<<<nb_u, 256, 0, stream>>>(deg_usr, n_usr, bsum_u, off_usr);

    hipMemsetAsync(deg_ent, 0, (size_t)(n_ent + n_usr) * sizeof(unsigned int), stream);
    kg_scatter_kernel<<<(Ekg + 255) / 256, 256, 0, stream>>>(
        head, tail, edge_type, Ekg, off_ent, deg_ent, packed);
    ui_scatter_kernel<<<(Eui + 255) / 256, 256, 0, stream>>>(
        uu, ii, inter_w, Eui, off_usr, deg_usr, sorted_i, sorted_w);

    // ---- hop-0 tables from original embeddings ----
    entity_tables_kernel<<<(n_ent + 15) / 16, 256, 0, stream>>>(entity_emb, n_ent, w_all, S0);
    user_table_kernel<<<(n_usr + 15) / 16, 256, 0, stream>>>(user_emb, n_usr, w_all, su0);

    // ---- hop 0: also emits S1/su1 for hop 1, and res = init + y ----
    kg_fused_kernel<<<(n_ent + 3) / 4, 256, 0, stream>>>(
        off_ent, packed, S0, entity_emb, relemb, w_all, n_ent,
        eaggA, S1, out_ent, entity_emb);
    ui_fused_kernel<<<(n_usr + 3) / 4, 256, 0, stream>>>(
        off_usr, sorted_i, sorted_w, su0, S0, entity_emb, w_all, n_usr,
        uaggA, su1, out_usr, user_emb);

    // ---- hop 1: res += y ----
    kg_fused_kernel<<<(n_ent + 3) / 4, 256, 0, stream>>>(
        off_ent, packed, S1, eaggA, relemb, w_all, n_ent,
        eaggB, nullptr, out_ent, nullptr);
    ui_fused_kernel<<<(n_usr + 3) / 4, 256, 0, stream>>>(
        off_usr, sorted_i, sorted_w, su1, S1, eaggA, w_all, n_usr,
        uaggB, nullptr, out_usr, nullptr);
}

// Round 7
// 569.857 us; speedup vs baseline: 2.8564x; 1.0971x over previous
//
#include <hip/hip_runtime.h>

// ---------- helpers ----------

__device__ __forceinline__ float red16(float p) {
    p += __shfl_xor(p, 1, 64);
    p += __shfl_xor(p, 2, 64);
    p += __shfl_xor(p, 4, 64);
    p += __shfl_xor(p, 8, 64);
    return p;
}

// ---------- setup kernels ----------

// w_all[r][k] = sum_c W_Q[k][c] * relemb[r][c]  for r=0..8 (edge_type-1)
// w_all[9][k] = sum_c W_UI[k][c] * relemb[edge_type[E-1]-1][c]   (rel_last)
__global__ void compute_w_kernel(const float* __restrict__ WQ,
                                 const float* __restrict__ WUI,
                                 const float* __restrict__ relemb,
                                 const int* __restrict__ etype, int Ekg,
                                 float* __restrict__ w_all) {
    int k = threadIdx.x; // 0..63
    for (int r = 0; r < 9; ++r) {
        float acc = 0.f;
#pragma unroll
        for (int c = 0; c < 64; ++c)
            acc = fmaf(WQ[k * 64 + c], relemb[r * 64 + c], acc);
        w_all[r * 64 + k] = acc;
    }
    int rl = etype[Ekg - 1] - 1;
    float acc = 0.f;
#pragma unroll
    for (int c = 0; c < 64; ++c)
        acc = fmaf(WUI[k * 64 + c], relemb[rl * 64 + c], acc);
    w_all[9 * 64 + k] = acc;
}

// S[i*10 + r] = E[i] . w_all[r]; 16 rows per block (16-lane groups)
__global__ void entity_tables_kernel(const float* __restrict__ E, int n_ent,
                                     const float* __restrict__ w_all,
                                     float* __restrict__ S) {
    __shared__ float4 w4[160];
    for (int i = threadIdx.x; i < 160; i += blockDim.x)
        w4[i] = ((const float4*)w_all)[i];
    __syncthreads();
    int l16 = threadIdx.x & 15;
    int row = blockIdx.x * 16 + (threadIdx.x >> 4);
    float4 ev = make_float4(0.f, 0.f, 0.f, 0.f);
    if (row < n_ent) ev = ((const float4*)E)[(size_t)row * 16 + l16];
#pragma unroll
    for (int r = 0; r < 10; ++r) {
        float4 wv = w4[r * 16 + l16];
        float p = ev.x * wv.x + ev.y * wv.y + ev.z * wv.z + ev.w * wv.w;
        p = red16(p);
        if (l16 == 0 && row < n_ent) S[(size_t)row * 10 + r] = p;
    }
}

// su[u] = U[u] . w_all[9]; 16 rows per block
__global__ void user_table_kernel(const float* __restrict__ U, int n_usr,
                                  const float* __restrict__ w_all,
                                  float* __restrict__ su) {
    __shared__ float4 w9[16];
    if (threadIdx.x < 16) w9[threadIdx.x] = ((const float4*)w_all)[144 + threadIdx.x];
    __syncthreads();
    int l16 = threadIdx.x & 15;
    int row = blockIdx.x * 16 + (threadIdx.x >> 4);
    float4 ev = make_float4(0.f, 0.f, 0.f, 0.f);
    if (row < n_usr) ev = ((const float4*)U)[(size_t)row * 16 + l16];
    float4 wv = w9[l16];
    float p = ev.x * wv.x + ev.y * wv.y + ev.z * wv.z + ev.w * wv.w;
    p = red16(p);
    if (l16 == 0 && row < n_usr) su[row] = p;
}

// ---------- CSR build ----------

__global__ void hist_kernel(const int* __restrict__ idx, int E,
                            unsigned int* __restrict__ deg) {
    int e = blockIdx.x * blockDim.x + threadIdx.x;
    if (e < E) atomicAdd(&deg[idx[e]], 1u);
}

#define SCAN_CHUNK 2048

__global__ void scan_pass1(const unsigned int* __restrict__ deg, int n,
                           unsigned int* __restrict__ bsums) {
    int base = blockIdx.x * SCAN_CHUNK;
    int tid = threadIdx.x;
    unsigned int s = 0;
#pragma unroll
    for (int j = 0; j < 8; ++j) {
        int i = base + tid * 8 + j;
        if (i < n) s += deg[i];
    }
#pragma unroll
    for (int off = 32; off > 0; off >>= 1)
        s += __shfl_xor(s, off, 64);
    __shared__ unsigned int wsm[4];
    if ((tid & 63) == 0) wsm[tid >> 6] = s;
    __syncthreads();
    if (tid == 0) bsums[blockIdx.x] = wsm[0] + wsm[1] + wsm[2] + wsm[3];
}

__global__ void scan_pass2(unsigned int* __restrict__ bsums, int nb) {
    __shared__ unsigned int tmp[1024];
    int tid = threadIdx.x;
    unsigned int v = (tid < nb) ? bsums[tid] : 0u;
    tmp[tid] = v;
    __syncthreads();
    for (int s = 1; s < 1024; s <<= 1) {
        unsigned int add = (tid >= s) ? tmp[tid - s] : 0u;
        __syncthreads();
        tmp[tid] += add;
        __syncthreads();
    }
    if (tid < nb) bsums[tid] = tmp[tid] - v; // exclusive
}

__global__ void scan_pass3(const unsigned int* __restrict__ deg, int n,
                           const unsigned int* __restrict__ bsums,
                           unsigned int* __restrict__ off) {
    int base = blockIdx.x * SCAN_CHUNK;
    int tid = threadIdx.x;
    int lane = tid & 63, wv = tid >> 6;
    unsigned int x[8];
    unsigned int s = 0;
#pragma unroll
    for (int j = 0; j < 8; ++j) {
        int i = base + tid * 8 + j;
        x[j] = (i < n) ? deg[i] : 0u;
        s += x[j];
    }
    unsigned int sc = s;
#pragma unroll
    for (int o = 1; o < 64; o <<= 1) {
        unsigned int t = __shfl_up(sc, o, 64);
        if (lane >= o) sc += t;
    }
    __shared__ unsigned int wtot[4];
    if (lane == 63) wtot[wv] = sc;
    __syncthreads();
    unsigned int woff = 0;
    for (int w = 0; w < wv; ++w) woff += wtot[w];
    unsigned int run = bsums[blockIdx.x] + woff + (sc - s);
#pragma unroll
    for (int j = 0; j < 8; ++j) {
        int i = base + tid * 8 + j;
        run += x[j];
        if (i < n) off[i + 1] = run;
    }
    if (blockIdx.x == 0 && tid == 0) off[0] = 0;
}

__global__ void kg_scatter_kernel(const int* __restrict__ head,
                                  const int* __restrict__ tail,
                                  const int* __restrict__ etype, int E,
                                  const unsigned int* __restrict__ off,
                                  unsigned int* __restrict__ cur,
                                  unsigned int* __restrict__ packed) {
    int e = blockIdx.x * blockDim.x + threadIdx.x;
    if (e >= E) return;
    int h = head[e];
    unsigned int pos = off[h] + atomicAdd(&cur[h], 1u);
    packed[pos] = (unsigned int)tail[e] | (((unsigned int)(etype[e] - 1)) << 20);
}

__global__ void ui_scatter_kernel(const int* __restrict__ uu,
                                  const int* __restrict__ ii,
                                  const float* __restrict__ iw, int E,
                                  const unsigned int* __restrict__ off,
                                  unsigned int* __restrict__ cur,
                                  unsigned int* __restrict__ sorted_i,
                                  float* __restrict__ sorted_w) {
    int e = blockIdx.x * blockDim.x + threadIdx.x;
    if (e >= E) return;
    int u = uu[e];
    unsigned int pos = off[u] + atomicAdd(&cur[u], 1u);
    sorted_i[pos] = (unsigned int)ii[e];
    sorted_w[pos] = iw[e];
}

// ---------- fused per-hop aggregation: kg blocks then ui blocks ----------
// 16-lane group per destination row; no max-subtraction (scores bounded:
// hop0 |sc|<~7, hop1 inputs L2-normalized -> |sc|<=2; exp() safe in fp32).

__global__ void hop_fused_kernel(
    const unsigned int* __restrict__ off_e,
    const unsigned int* __restrict__ packed,
    const float* __restrict__ S,
    const float* __restrict__ relemb,
    int n_ent, int nbe,
    float* __restrict__ eagg, float* __restrict__ Snext,
    float* __restrict__ res_e, const float* __restrict__ res_init_e,
    const unsigned int* __restrict__ off_u,
    const unsigned int* __restrict__ sorted_i,
    const float* __restrict__ sorted_w,
    const float* __restrict__ su, int n_usr,
    float* __restrict__ uagg, float* __restrict__ sunext,
    float* __restrict__ res_u, const float* __restrict__ res_init_u,
    const float* __restrict__ Eemb,
    const float* __restrict__ w_all) {
    __shared__ float4 rel4[144]; // 9 x 16
    __shared__ float4 w4[160];   // 10 x 16
    for (int i = threadIdx.x; i < 144; i += blockDim.x)
        rel4[i] = ((const float4*)relemb)[i];
    for (int i = threadIdx.x; i < 160; i += blockDim.x)
        w4[i] = ((const float4*)w_all)[i];
    __syncthreads();

    int lane = threadIdx.x & 63;
    int l16 = lane & 15;
    int gbase = lane & 48; // group base within wave for shfl

    bool is_kg = (int)blockIdx.x < nbe;

    if (is_kg) {
        int h = blockIdx.x * 16 + (threadIdx.x >> 4);
        if (h >= n_ent) return;
        unsigned int s0 = off_e[h], s1 = off_e[h + 1];
        unsigned int cnt = s1 - s0;
        float shv = (l16 < 10) ? S[(size_t)h * 10 + l16] : 0.f;

        float4 acc = make_float4(0.f, 0.f, 0.f, 0.f);
        float wsum = 0.f;
        if (cnt <= 16) {
            // lane-parallel scoring; shfl executed at full convergence
            // (inactive lanes use pk=0 -> t=0,r=0 dummy safe loads)
            unsigned int pk = (l16 < (int)cnt) ? packed[s0 + l16] : 0u;
            int t = pk & 0xFFFFF, r = pk >> 20;
            float st = S[(size_t)t * 10 + r];
            float q = __shfl(shv, gbase + r, 64);   // all lanes participate
            float wg = (l16 < (int)cnt) ? __expf(q + st) : 0.f;
            wsum = red16(wg); // group-uniform
            for (unsigned int j = 0; j < cnt; ++j) {
                unsigned int pkj = (unsigned int)__shfl((int)pk, gbase + (int)j, 64);
                float wgj = __shfl(wg, gbase + (int)j, 64);
                int tj = pkj & 0xFFFFF, rj = pkj >> 20;
                float4 ev = ((const float4*)(Eemb + (size_t)tj * 64))[l16];
                float4 rv = rel4[rj * 16 + l16];
                acc.x = fmaf(wgj, ev.x * rv.x, acc.x);
                acc.y = fmaf(wgj, ev.y * rv.y, acc.y);
                acc.z = fmaf(wgj, ev.z * rv.z, acc.z);
                acc.w = fmaf(wgj, ev.w * rv.w, acc.w);
            }
        } else {
            for (unsigned int j = 0; j < cnt; ++j) {
                unsigned int pkj = packed[s0 + j]; // broadcast
                int t = pkj & 0xFFFFF, r = pkj >> 20;
                float st = S[(size_t)t * 10 + r];
                float sc = __shfl(shv, gbase + r, 64) + st;
                float wgj = __expf(sc); // uniform within group
                wsum += wgj;
                float4 ev = ((const float4*)(Eemb + (size_t)t * 64))[l16];
                float4 rv = rel4[r * 16 + l16];
                acc.x = fmaf(wgj, ev.x * rv.x, acc.x);
                acc.y = fmaf(wgj, ev.y * rv.y, acc.y);
                acc.z = fmaf(wgj, ev.z * rv.z, acc.z);
                acc.w = fmaf(wgj, ev.w * rv.w, acc.w);
            }
        }
        float inv = 1.f / (wsum + 1e-16f);
        float4 y = make_float4(acc.x * inv, acc.y * inv, acc.z * inv, acc.w * inv);
        float ss = red16(y.x * y.x + y.y * y.y + y.z * y.z + y.w * y.w);
        float sinv = 1.f / fmaxf(sqrtf(ss), 1e-12f);
        y.x *= sinv; y.y *= sinv; y.z *= sinv; y.w *= sinv;

        size_t ro = (size_t)h * 16 + l16;
        ((float4*)eagg)[ro] = y;
        float4 b4 = res_init_e ? ((const float4*)res_init_e)[ro]
                               : ((const float4*)res_e)[ro];
        ((float4*)res_e)[ro] = make_float4(b4.x + y.x, b4.y + y.y,
                                           b4.z + y.z, b4.w + y.w);
        if (Snext) {
#pragma unroll
            for (int r2 = 0; r2 < 10; ++r2) {
                float4 wv = w4[r2 * 16 + l16];
                float p = red16(y.x * wv.x + y.y * wv.y + y.z * wv.z + y.w * wv.w);
                if (l16 == 0) Snext[(size_t)h * 10 + r2] = p;
            }
        }
    } else {
        int u = (blockIdx.x - nbe) * 16 + (threadIdx.x >> 4);
        if (u >= n_usr) return;
        unsigned int s0 = off_u[u], s1 = off_u[u + 1];
        unsigned int cnt = s1 - s0;
        float squ = su[u];

        float4 acc = make_float4(0.f, 0.f, 0.f, 0.f);
        float wsum = 0.f;
        if (cnt <= 16) {
            unsigned int iv = 0; float wg = 0.f, cw = 0.f;
            if (l16 < (int)cnt) {
                iv = sorted_i[s0 + l16];
                float sw = sorted_w[s0 + l16];
                float sc = squ + S[(size_t)iv * 10 + 9];
                wg = __expf(sc);
                cw = wg * sw;
            }
            wsum = red16(wg);
            for (unsigned int j = 0; j < cnt; ++j) {
                unsigned int ij = (unsigned int)__shfl((int)iv, gbase + (int)j, 64);
                float cwj = __shfl(cw, gbase + (int)j, 64);
                float4 ev = ((const float4*)(Eemb + (size_t)ij * 64))[l16];
                acc.x = fmaf(cwj, ev.x, acc.x);
                acc.y = fmaf(cwj, ev.y, acc.y);
                acc.z = fmaf(cwj, ev.z, acc.z);
                acc.w = fmaf(cwj, ev.w, acc.w);
            }
        } else {
            for (unsigned int j = 0; j < cnt; ++j) {
                unsigned int ij = sorted_i[s0 + j]; // broadcast
                float swj = sorted_w[s0 + j];
                float sc = squ + S[(size_t)ij * 10 + 9];
                float wgj = __expf(sc);
                wsum += wgj;
                float cwj = wgj * swj;
                float4 ev = ((const float4*)(Eemb + (size_t)ij * 64))[l16];
                acc.x = fmaf(cwj, ev.x, acc.x);
                acc.y = fmaf(cwj, ev.y, acc.y);
                acc.z = fmaf(cwj, ev.z, acc.z);
                acc.w = fmaf(cwj, ev.w, acc.w);
            }
        }
        float inv = 1.f / (wsum + 1e-16f);
        float4 y = make_float4(acc.x * inv, acc.y * inv, acc.z * inv, acc.w * inv);
        float ss = red16(y.x * y.x + y.y * y.y + y.z * y.z + y.w * y.w);
        float sinv = 1.f / fmaxf(sqrtf(ss), 1e-12f);
        y.x *= sinv; y.y *= sinv; y.z *= sinv; y.w *= sinv;

        size_t ro = (size_t)u * 16 + l16;
        ((float4*)uagg)[ro] = y;
        float4 b4 = res_init_u ? ((const float4*)res_init_u)[ro]
                               : ((const float4*)res_u)[ro];
        ((float4*)res_u)[ro] = make_float4(b4.x + y.x, b4.y + y.y,
                                           b4.z + y.z, b4.w + y.w);
        if (sunext) {
            float4 wv = w4[144 + l16];
            float p = red16(y.x * wv.x + y.y * wv.y + y.z * wv.z + y.w * wv.w);
            if (l16 == 0) sunext[u] = p;
        }
    }
}

// ---------- launch ----------

extern "C" void kernel_launch(void* const* d_in, const int* in_sizes, int n_in,
                              void* d_out, int out_size, void* d_ws, size_t ws_size,
                              hipStream_t stream) {
    const float* user_emb   = (const float*)d_in[0];
    const float* entity_emb = (const float*)d_in[1];
    const int*   edge_index = (const int*)d_in[2];
    const int*   edge_type  = (const int*)d_in[3];
    const int*   inter_edge = (const int*)d_in[4];
    const float* inter_w    = (const float*)d_in[5];
    const float* relemb     = (const float*)d_in[6];
    const float* WQ         = (const float*)d_in[7];
    const float* WUI        = (const float*)d_in[8];

    const int C = 64;
    const int n_usr = in_sizes[0] / C;
    const int n_ent = in_sizes[1] / C;
    const int Ekg   = in_sizes[3];
    const int Eui   = in_sizes[5];
    const int* head = edge_index;
    const int* tail = edge_index + Ekg;
    const int* uu   = inter_edge;
    const int* ii   = inter_edge + Eui;

    float* ws = (float*)d_ws;
    float* w_all = ws;                          ws += 640;
    float* S0    = ws;                          ws += (size_t)n_ent * 10;
    float* S1    = ws;                          ws += (size_t)n_ent * 10;
    float* su0   = ws;                          ws += n_usr;
    float* su1   = ws;                          ws += n_usr;
    unsigned int* deg_ent = (unsigned int*)ws;  ws += n_ent;   // also cursor
    unsigned int* deg_usr = (unsigned int*)ws;  ws += n_usr;   // also cursor
    unsigned int* off_ent = (unsigned int*)ws;  ws += n_ent + 1;
    unsigned int* off_usr = (unsigned int*)ws;  ws += n_usr + 1;
    unsigned int* bsum_e  = (unsigned int*)ws;  ws += 1024;
    unsigned int* bsum_u  = (unsigned int*)ws;  ws += 1024;
    unsigned int* packed  = (unsigned int*)ws;  ws += Ekg;
    unsigned int* sorted_i = (unsigned int*)ws; ws += Eui;
    float* sorted_w = ws;                       ws += Eui;
    float* eaggA = ws;                          ws += (size_t)n_ent * C;
    float* uaggA = ws;                          ws += (size_t)n_usr * C;
    float* eaggB = ws;                          ws += (size_t)n_ent * C;
    float* uaggB = ws;                          ws += (size_t)n_usr * C;

    float* out_ent = (float*)d_out;
    float* out_usr = out_ent + (size_t)n_ent * C;

    compute_w_kernel<<<1, 64, 0, stream>>>(WQ, WUI, relemb, edge_type, Ekg, w_all);

    // ---- CSR build (edges static across hops) ----
    hipMemsetAsync(deg_ent, 0, (size_t)(n_ent + n_usr) * sizeof(unsigned int), stream);
    hist_kernel<<<(Ekg + 255) / 256, 256, 0, stream>>>(head, Ekg, deg_ent);
    hist_kernel<<<(Eui + 255) / 256, 256, 0, stream>>>(uu, Eui, deg_usr);

    int nb_e = (n_ent + SCAN_CHUNK - 1) / SCAN_CHUNK;
    int nb_u = (n_usr + SCAN_CHUNK - 1) / SCAN_CHUNK;
    scan_pass1<<<nb_e, 256, 0, stream>>>(deg_ent, n_ent, bsum_e);
    scan_pass2<<<1, 1024, 0, stream>>>(bsum_e, nb_e);
    scan_pass3<<<nb_e, 256, 0, stream>>>(deg_ent, n_ent, bsum_e, off_ent);
    scan_pass1<<<nb_u, 256, 0, stream>>>(deg_usr, n_usr, bsum_u);
    scan_pass2<<<1, 1024, 0, stream>>>(bsum_u, nb_u);
    scan_pass3<<<nb_u, 256, 0, stream>>>(deg_usr, n_usr, bsum_u, off_usr);

    hipMemsetAsync(deg_ent, 0, (size_t)(n_ent + n_usr) * sizeof(unsigned int), stream);
    kg_scatter_kernel<<<(Ekg + 255) / 256, 256, 0, stream>>>(
        head, tail, edge_type, Ekg, off_ent, deg_ent, packed);
    ui_scatter_kernel<<<(Eui + 255) / 256, 256, 0, stream>>>(
        uu, ii, inter_w, Eui, off_usr, deg_usr, sorted_i, sorted_w);

    // ---- hop-0 tables from original embeddings ----
    entity_tables_kernel<<<(n_ent + 15) / 16, 256, 0, stream>>>(entity_emb, n_ent, w_all, S0);
    user_table_kernel<<<(n_usr + 15) / 16, 256, 0, stream>>>(user_emb, n_usr, w_all, su0);

    int nbe = (n_ent + 15) / 16;
    int nbu = (n_usr + 15) / 16;

    // ---- hop 0: emits S1/su1 for hop 1; res = init + y ----
    hop_fused_kernel<<<nbe + nbu, 256, 0, stream>>>(
        off_ent, packed, S0, relemb, n_ent, nbe,
        eaggA, S1, out_ent, entity_emb,
        off_usr, sorted_i, sorted_w, su0, n_usr,
        uaggA, su1, out_usr, user_emb,
        entity_emb, w_all);

    // ---- hop 1: res += y ----
    hop_fused_kernel<<<nbe + nbu, 256, 0, stream>>>(
        off_ent, packed, S1, relemb, n_ent, nbe,
        eaggB, nullptr, out_ent, nullptr,
        off_usr, sorted_i, sorted_w, su1, n_usr,
        uaggB, nullptr, out_usr, nullptr,
        eaggA, w_all);
}

// Round 8
// 530.639 us; speedup vs baseline: 3.0676x; 1.0739x over previous
//
#include <hip/hip_runtime.h>

// ---------- helpers ----------

__device__ __forceinline__ float red16(float p) {
    p += __shfl_xor(p, 1, 64);
    p += __shfl_xor(p, 2, 64);
    p += __shfl_xor(p, 4, 64);
    p += __shfl_xor(p, 8, 64);
    return p;
}

// ---------- setup kernels ----------

// 640 threads: thread = r*64+k. w_all[r][k] = sum_c W_Q[k][c]*relemb[r][c]
// (r<9); w_all[9][k] = sum_c W_UI[k][c]*relemb[etype[E-1]-1][c].
__global__ void compute_w_kernel(const float* __restrict__ WQ,
                                 const float* __restrict__ WUI,
                                 const float* __restrict__ relemb,
                                 const int* __restrict__ etype, int Ekg,
                                 float* __restrict__ w_all) {
    int tid = threadIdx.x;
    if (tid >= 640) return;
    int r = tid >> 6, k = tid & 63;
    const float* M = (r == 9) ? WUI : WQ;
    int rr = (r == 9) ? (etype[Ekg - 1] - 1) : r;
    float acc = 0.f;
#pragma unroll
    for (int c = 0; c < 64; ++c)
        acc = fmaf(M[k * 64 + c], relemb[rr * 64 + c], acc);
    w_all[r * 64 + k] = acc;
}

// merged tables: blocks [0,nbe) entity S (10 dots), [nbe,nbe+nbu) user su
__global__ void tables_kernel(const float* __restrict__ E, int n_ent, int nbe,
                              const float* __restrict__ U, int n_usr,
                              const float* __restrict__ w_all,
                              float* __restrict__ S, float* __restrict__ su) {
    __shared__ float4 w4[160];
    for (int i = threadIdx.x; i < 160; i += blockDim.x)
        w4[i] = ((const float4*)w_all)[i];
    __syncthreads();
    int l16 = threadIdx.x & 15;
    if ((int)blockIdx.x < nbe) {
        int row = blockIdx.x * 16 + (threadIdx.x >> 4);
        float4 ev = make_float4(0.f, 0.f, 0.f, 0.f);
        if (row < n_ent) ev = ((const float4*)E)[(size_t)row * 16 + l16];
#pragma unroll
        for (int r = 0; r < 10; ++r) {
            float4 wv = w4[r * 16 + l16];
            float p = ev.x * wv.x + ev.y * wv.y + ev.z * wv.z + ev.w * wv.w;
            p = red16(p);
            if (l16 == 0 && row < n_ent) S[(size_t)row * 10 + r] = p;
        }
    } else {
        int row = (blockIdx.x - nbe) * 16 + (threadIdx.x >> 4);
        float4 ev = make_float4(0.f, 0.f, 0.f, 0.f);
        if (row < n_usr) ev = ((const float4*)U)[(size_t)row * 16 + l16];
        float4 wv = w4[144 + l16];
        float p = ev.x * wv.x + ev.y * wv.y + ev.z * wv.z + ev.w * wv.w;
        p = red16(p);
        if (l16 == 0 && row < n_usr) su[row] = p;
    }
}

// ---------- CSR build (merged ent+usr) ----------

__global__ void hist2_kernel(const int* __restrict__ ia, int Ea,
                             unsigned int* __restrict__ dega,
                             const int* __restrict__ ib, int Eb,
                             unsigned int* __restrict__ degb) {
    int e = blockIdx.x * blockDim.x + threadIdx.x;
    if (e < Ea) atomicAdd(&dega[ia[e]], 1u);
    else if (e < Ea + Eb) atomicAdd(&degb[ib[e - Ea]], 1u);
}

#define SCAN_CHUNK 2048

__device__ __forceinline__ void scan1_body(const unsigned int* deg, int n,
                                           unsigned int* bsums, int blk) {
    int base = blk * SCAN_CHUNK;
    int tid = threadIdx.x;
    unsigned int s = 0;
#pragma unroll
    for (int j = 0; j < 8; ++j) {
        int i = base + tid * 8 + j;
        if (i < n) s += deg[i];
    }
#pragma unroll
    for (int off = 32; off > 0; off >>= 1)
        s += __shfl_xor(s, off, 64);
    __shared__ unsigned int wsm[4];
    if ((tid & 63) == 0) wsm[tid >> 6] = s;
    __syncthreads();
    if (tid == 0) bsums[blk] = wsm[0] + wsm[1] + wsm[2] + wsm[3];
}

__global__ void scan_pass1(const unsigned int* __restrict__ dega, int na, int nba,
                           unsigned int* __restrict__ bsa,
                           const unsigned int* __restrict__ degb, int nb_,
                           unsigned int* __restrict__ bsb) {
    if ((int)blockIdx.x < nba) scan1_body(dega, na, bsa, blockIdx.x);
    else scan1_body(degb, nb_, bsb, blockIdx.x - nba);
}

__device__ __forceinline__ void scan2_body(unsigned int* bsums, int nb) {
    __shared__ unsigned int tmp[1024];
    int tid = threadIdx.x;
    unsigned int v = (tid < nb) ? bsums[tid] : 0u;
    tmp[tid] = v;
    __syncthreads();
    for (int s = 1; s < 1024; s <<= 1) {
        unsigned int add = (tid >= s) ? tmp[tid - s] : 0u;
        __syncthreads();
        tmp[tid] += add;
        __syncthreads();
    }
    if (tid < nb) bsums[tid] = tmp[tid] - v; // exclusive
}

__global__ void scan_pass2(unsigned int* __restrict__ bsa, int nba,
                           unsigned int* __restrict__ bsb, int nbb) {
    if (blockIdx.x == 0) scan2_body(bsa, nba);
    else scan2_body(bsb, nbb);
}

__device__ __forceinline__ void scan3_body(const unsigned int* deg, int n,
                                           const unsigned int* bsums,
                                           unsigned int* off, int blk) {
    int base = blk * SCAN_CHUNK;
    int tid = threadIdx.x;
    int lane = tid & 63, wv = tid >> 6;
    unsigned int x[8];
    unsigned int s = 0;
#pragma unroll
    for (int j = 0; j < 8; ++j) {
        int i = base + tid * 8 + j;
        x[j] = (i < n) ? deg[i] : 0u;
        s += x[j];
    }
    unsigned int sc = s;
#pragma unroll
    for (int o = 1; o < 64; o <<= 1) {
        unsigned int t = __shfl_up(sc, o, 64);
        if (lane >= o) sc += t;
    }
    __shared__ unsigned int wtot[4];
    if (lane == 63) wtot[wv] = sc;
    __syncthreads();
    unsigned int woff = 0;
    for (int w = 0; w < wv; ++w) woff += wtot[w];
    unsigned int run = bsums[blk] + woff + (sc - s);
#pragma unroll
    for (int j = 0; j < 8; ++j) {
        int i = base + tid * 8 + j;
        run += x[j];
        if (i < n) off[i + 1] = run;
    }
    if (blk == 0 && tid == 0) off[0] = 0;
}

__global__ void scan_pass3(const unsigned int* __restrict__ dega, int na, int nba,
                           const unsigned int* __restrict__ bsa,
                           unsigned int* __restrict__ offa,
                           const unsigned int* __restrict__ degb, int nb_,
                           const unsigned int* __restrict__ bsb,
                           unsigned int* __restrict__ offb) {
    if ((int)blockIdx.x < nba) scan3_body(dega, na, bsa, offa, blockIdx.x);
    else scan3_body(degb, nb_, bsb, offb, blockIdx.x - nba);
}

__global__ void scatter2_kernel(const int* __restrict__ head,
                                const int* __restrict__ tail,
                                const int* __restrict__ etype, int Ekg,
                                const unsigned int* __restrict__ off_e,
                                unsigned int* __restrict__ cur_e,
                                unsigned int* __restrict__ packed,
                                const int* __restrict__ uu,
                                const int* __restrict__ ii,
                                const float* __restrict__ iw, int Eui,
                                const unsigned int* __restrict__ off_u,
                                unsigned int* __restrict__ cur_u,
                                unsigned int* __restrict__ sorted_i,
                                float* __restrict__ sorted_w) {
    int e = blockIdx.x * blockDim.x + threadIdx.x;
    if (e < Ekg) {
        int h = head[e];
        unsigned int pos = off_e[h] + atomicAdd(&cur_e[h], 1u);
        packed[pos] = (unsigned int)tail[e] | (((unsigned int)(etype[e] - 1)) << 20);
    } else if (e < Ekg + Eui) {
        int e2 = e - Ekg;
        int u = uu[e2];
        unsigned int pos = off_u[u] + atomicAdd(&cur_u[u], 1u);
        sorted_i[pos] = (unsigned int)ii[e2];
        sorted_w[pos] = iw[e2];
    }
}

// ---------- fused per-hop aggregation: kg blocks then ui blocks ----------
// 16-lane group per destination row; chunked lane-parallel scoring; 2x
// unrolled row-gather (two independent accumulators for MLP). No
// max-subtraction (scores bounded; exp safe in fp32 — verified R7).

__global__ void hop_fused_kernel(
    const unsigned int* __restrict__ off_e,
    const unsigned int* __restrict__ packed,
    const float* __restrict__ S,
    const float* __restrict__ relemb,
    int n_ent, int nbe,
    float* __restrict__ eagg, float* __restrict__ Snext,
    float* __restrict__ res_e, const float* __restrict__ res_init_e,
    const unsigned int* __restrict__ off_u,
    const unsigned int* __restrict__ sorted_i,
    const float* __restrict__ sorted_w,
    const float* __restrict__ su, int n_usr,
    float* __restrict__ uagg, float* __restrict__ sunext,
    float* __restrict__ res_u, const float* __restrict__ res_init_u,
    const float* __restrict__ Eemb,
    const float* __restrict__ w_all) {
    __shared__ float4 rel4[144]; // 9 x 16
    __shared__ float4 w4[160];   // 10 x 16
    for (int i = threadIdx.x; i < 144; i += blockDim.x)
        rel4[i] = ((const float4*)relemb)[i];
    for (int i = threadIdx.x; i < 160; i += blockDim.x)
        w4[i] = ((const float4*)w_all)[i];
    __syncthreads();

    int lane = threadIdx.x & 63;
    int l16 = lane & 15;
    int gbase = lane & 48; // group base within wave for shfl

    if ((int)blockIdx.x < nbe) {
        int h = blockIdx.x * 16 + (threadIdx.x >> 4);
        if (h >= n_ent) return;
        unsigned int s0 = off_e[h], s1 = off_e[h + 1];
        float shv = (l16 < 10) ? S[(size_t)h * 10 + l16] : 0.f;

        float4 acc0 = make_float4(0.f, 0.f, 0.f, 0.f);
        float4 acc1 = make_float4(0.f, 0.f, 0.f, 0.f);
        float wsum = 0.f;
        for (unsigned int base = s0; base < s1; base += 16) {
            unsigned int rem = s1 - base;
            unsigned int c = rem < 16u ? rem : 16u;
            // lane-parallel scoring at full convergence
            unsigned int pk = (l16 < (int)c) ? packed[base + l16] : 0u;
            int t = pk & 0xFFFFF, r = pk >> 20;
            float st = S[(size_t)t * 10 + r];
            float q = __shfl(shv, gbase + r, 64);
            float wg = (l16 < (int)c) ? __expf(q + st) : 0.f;
            wsum += red16(wg); // group-uniform
            unsigned int j = 0;
            for (; j + 2 <= c; j += 2) {
                unsigned int p0 = (unsigned int)__shfl((int)pk, gbase + (int)j, 64);
                unsigned int p1 = (unsigned int)__shfl((int)pk, gbase + (int)j + 1, 64);
                float w0 = __shfl(wg, gbase + (int)j, 64);
                float w1 = __shfl(wg, gbase + (int)j + 1, 64);
                int t0 = p0 & 0xFFFFF, r0 = p0 >> 20;
                int t1 = p1 & 0xFFFFF, r1 = p1 >> 20;
                float4 e0 = ((const float4*)(Eemb + (size_t)t0 * 64))[l16];
                float4 e1 = ((const float4*)(Eemb + (size_t)t1 * 64))[l16];
                float4 v0 = rel4[r0 * 16 + l16];
                float4 v1 = rel4[r1 * 16 + l16];
                acc0.x = fmaf(w0, e0.x * v0.x, acc0.x);
                acc0.y = fmaf(w0, e0.y * v0.y, acc0.y);
                acc0.z = fmaf(w0, e0.z * v0.z, acc0.z);
                acc0.w = fmaf(w0, e0.w * v0.w, acc0.w);
                acc1.x = fmaf(w1, e1.x * v1.x, acc1.x);
                acc1.y = fmaf(w1, e1.y * v1.y, acc1.y);
                acc1.z = fmaf(w1, e1.z * v1.z, acc1.z);
                acc1.w = fmaf(w1, e1.w * v1.w, acc1.w);
            }
            if (j < c) {
                unsigned int p0 = (unsigned int)__shfl((int)pk, gbase + (int)j, 64);
                float w0 = __shfl(wg, gbase + (int)j, 64);
                int t0 = p0 & 0xFFFFF, r0 = p0 >> 20;
                float4 e0 = ((const float4*)(Eemb + (size_t)t0 * 64))[l16];
                float4 v0 = rel4[r0 * 16 + l16];
                acc0.x = fmaf(w0, e0.x * v0.x, acc0.x);
                acc0.y = fmaf(w0, e0.y * v0.y, acc0.y);
                acc0.z = fmaf(w0, e0.z * v0.z, acc0.z);
                acc0.w = fmaf(w0, e0.w * v0.w, acc0.w);
            }
        }
        float4 acc = make_float4(acc0.x + acc1.x, acc0.y + acc1.y,
                                 acc0.z + acc1.z, acc0.w + acc1.w);
        float inv = 1.f / (wsum + 1e-16f);
        float4 y = make_float4(acc.x * inv, acc.y * inv, acc.z * inv, acc.w * inv);
        float ss = red16(y.x * y.x + y.y * y.y + y.z * y.z + y.w * y.w);
        float sinv = 1.f / fmaxf(sqrtf(ss), 1e-12f);
        y.x *= sinv; y.y *= sinv; y.z *= sinv; y.w *= sinv;

        size_t ro = (size_t)h * 16 + l16;
        if (eagg) ((float4*)eagg)[ro] = y;
        float4 b4 = res_init_e ? ((const float4*)res_init_e)[ro]
                               : ((const float4*)res_e)[ro];
        ((float4*)res_e)[ro] = make_float4(b4.x + y.x, b4.y + y.y,
                                           b4.z + y.z, b4.w + y.w);
        if (Snext) {
#pragma unroll
            for (int r2 = 0; r2 < 10; ++r2) {
                float4 wv = w4[r2 * 16 + l16];
                float p = red16(y.x * wv.x + y.y * wv.y + y.z * wv.z + y.w * wv.w);
                if (l16 == 0) Snext[(size_t)h * 10 + r2] = p;
            }
        }
    } else {
        int u = (blockIdx.x - nbe) * 16 + (threadIdx.x >> 4);
        if (u >= n_usr) return;
        unsigned int s0 = off_u[u], s1 = off_u[u + 1];
        float squ = su[u];

        float4 acc0 = make_float4(0.f, 0.f, 0.f, 0.f);
        float4 acc1 = make_float4(0.f, 0.f, 0.f, 0.f);
        float wsum = 0.f;
        for (unsigned int base = s0; base < s1; base += 16) {
            unsigned int rem = s1 - base;
            unsigned int c = rem < 16u ? rem : 16u;
            unsigned int iv = 0; float wg = 0.f, cw = 0.f;
            if (l16 < (int)c) {
                iv = sorted_i[base + l16];
                float sw = sorted_w[base + l16];
                wg = __expf(squ + S[(size_t)iv * 10 + 9]);
                cw = wg * sw;
            }
            wsum += red16(wg);
            unsigned int j = 0;
            for (; j + 2 <= c; j += 2) {
                unsigned int i0 = (unsigned int)__shfl((int)iv, gbase + (int)j, 64);
                unsigned int i1 = (unsigned int)__shfl((int)iv, gbase + (int)j + 1, 64);
                float w0 = __shfl(cw, gbase + (int)j, 64);
                float w1 = __shfl(cw, gbase + (int)j + 1, 64);
                float4 e0 = ((const float4*)(Eemb + (size_t)i0 * 64))[l16];
                float4 e1 = ((const float4*)(Eemb + (size_t)i1 * 64))[l16];
                acc0.x = fmaf(w0, e0.x, acc0.x);
                acc0.y = fmaf(w0, e0.y, acc0.y);
                acc0.z = fmaf(w0, e0.z, acc0.z);
                acc0.w = fmaf(w0, e0.w, acc0.w);
                acc1.x = fmaf(w1, e1.x, acc1.x);
                acc1.y = fmaf(w1, e1.y, acc1.y);
                acc1.z = fmaf(w1, e1.z, acc1.z);
                acc1.w = fmaf(w1, e1.w, acc1.w);
            }
            if (j < c) {
                unsigned int i0 = (unsigned int)__shfl((int)iv, gbase + (int)j, 64);
                float w0 = __shfl(cw, gbase + (int)j, 64);
                float4 e0 = ((const float4*)(Eemb + (size_t)i0 * 64))[l16];
                acc0.x = fmaf(w0, e0.x, acc0.x);
                acc0.y = fmaf(w0, e0.y, acc0.y);
                acc0.z = fmaf(w0, e0.z, acc0.z);
                acc0.w = fmaf(w0, e0.w, acc0.w);
            }
        }
        float4 acc = make_float4(acc0.x + acc1.x, acc0.y + acc1.y,
                                 acc0.z + acc1.z, acc0.w + acc1.w);
        float inv = 1.f / (wsum + 1e-16f);
        float4 y = make_float4(acc.x * inv, acc.y * inv, acc.z * inv, acc.w * inv);
        float ss = red16(y.x * y.x + y.y * y.y + y.z * y.z + y.w * y.w);
        float sinv = 1.f / fmaxf(sqrtf(ss), 1e-12f);
        y.x *= sinv; y.y *= sinv; y.z *= sinv; y.w *= sinv;

        size_t ro = (size_t)u * 16 + l16;
        if (uagg) ((float4*)uagg)[ro] = y;
        float4 b4 = res_init_u ? ((const float4*)res_init_u)[ro]
                               : ((const float4*)res_u)[ro];
        ((float4*)res_u)[ro] = make_float4(b4.x + y.x, b4.y + y.y,
                                           b4.z + y.z, b4.w + y.w);
        if (sunext) {
            float4 wv = w4[144 + l16];
            float p = red16(y.x * wv.x + y.y * wv.y + y.z * wv.z + y.w * wv.w);
            if (l16 == 0) sunext[u] = p;
        }
    }
}

// ---------- launch ----------

extern "C" void kernel_launch(void* const* d_in, const int* in_sizes, int n_in,
                              void* d_out, int out_size, void* d_ws, size_t ws_size,
                              hipStream_t stream) {
    const float* user_emb   = (const float*)d_in[0];
    const float* entity_emb = (const float*)d_in[1];
    const int*   edge_index = (const int*)d_in[2];
    const int*   edge_type  = (const int*)d_in[3];
    const int*   inter_edge = (const int*)d_in[4];
    const float* inter_w    = (const float*)d_in[5];
    const float* relemb     = (const float*)d_in[6];
    const float* WQ         = (const float*)d_in[7];
    const float* WUI        = (const float*)d_in[8];

    const int C = 64;
    const int n_usr = in_sizes[0] / C;
    const int n_ent = in_sizes[1] / C;
    const int Ekg   = in_sizes[3];
    const int Eui   = in_sizes[5];
    const int* head = edge_index;
    const int* tail = edge_index + Ekg;
    const int* uu   = inter_edge;
    const int* ii   = inter_edge + Eui;

    float* ws = (float*)d_ws;
    float* w_all = ws;                          ws += 640;
    float* S0    = ws;                          ws += (size_t)n_ent * 10;
    float* S1    = ws;                          ws += (size_t)n_ent * 10;
    float* su0   = ws;                          ws += n_usr;
    float* su1   = ws;                          ws += n_usr;
    unsigned int* deg_ent = (unsigned int*)ws;  ws += n_ent;   // also cursor
    unsigned int* deg_usr = (unsigned int*)ws;  ws += n_usr;   // also cursor
    unsigned int* off_ent = (unsigned int*)ws;  ws += n_ent + 1;
    unsigned int* off_usr = (unsigned int*)ws;  ws += n_usr + 1;
    unsigned int* bsum_e  = (unsigned int*)ws;  ws += 1024;
    unsigned int* bsum_u  = (unsigned int*)ws;  ws += 1024;
    unsigned int* packed  = (unsigned int*)ws;  ws += Ekg;
    unsigned int* sorted_i = (unsigned int*)ws; ws += Eui;
    float* sorted_w = ws;                       ws += Eui;
    float* eaggA = ws;                          ws += (size_t)n_ent * C;
    float* uaggA = ws;                          ws += (size_t)n_usr * C;

    float* out_ent = (float*)d_out;
    float* out_usr = out_ent + (size_t)n_ent * C;

    compute_w_kernel<<<1, 640, 0, stream>>>(WQ, WUI, relemb, edge_type, Ekg, w_all);

    // ---- CSR build (edges static across hops) ----
    hipMemsetAsync(deg_ent, 0, (size_t)(n_ent + n_usr) * sizeof(unsigned int), stream);
    hist2_kernel<<<(Ekg + Eui + 255) / 256, 256, 0, stream>>>(
        head, Ekg, deg_ent, uu, Eui, deg_usr);

    int nb_e = (n_ent + SCAN_CHUNK - 1) / SCAN_CHUNK;
    int nb_u = (n_usr + SCAN_CHUNK - 1) / SCAN_CHUNK;
    scan_pass1<<<nb_e + nb_u, 256, 0, stream>>>(deg_ent, n_ent, nb_e, bsum_e,
                                                deg_usr, n_usr, bsum_u);
    scan_pass2<<<2, 1024, 0, stream>>>(bsum_e, nb_e, bsum_u, nb_u);
    scan_pass3<<<nb_e + nb_u, 256, 0, stream>>>(deg_ent, n_ent, nb_e, bsum_e, off_ent,
                                                deg_usr, n_usr, bsum_u, off_usr);

    hipMemsetAsync(deg_ent, 0, (size_t)(n_ent + n_usr) * sizeof(unsigned int), stream);
    scatter2_kernel<<<(Ekg + Eui + 255) / 256, 256, 0, stream>>>(
        head, tail, edge_type, Ekg, off_ent, deg_ent, packed,
        uu, ii, inter_w, Eui, off_usr, deg_usr, sorted_i, sorted_w);

    int nbe = (n_ent + 15) / 16;
    int nbu = (n_usr + 15) / 16;

    // ---- hop-0 tables from original embeddings ----
    tables_kernel<<<nbe + nbu, 256, 0, stream>>>(
        entity_emb, n_ent, nbe, user_emb, n_usr, w_all, S0, su0);

    // ---- hop 0: emits S1/su1 for hop 1; res = init + y ----
    hop_fused_kernel<<<nbe + nbu, 256, 0, stream>>>(
        off_ent, packed, S0, relemb, n_ent, nbe,
        eaggA, S1, out_ent, entity_emb,
        off_usr, sorted_i, sorted_w, su0, n_usr,
        uaggA, su1, out_usr, user_emb,
        entity_emb, w_all);

    // ---- hop 1: res += y (agg outputs dead -> skipped) ----
    hop_fused_kernel<<<nbe + nbu, 256, 0, stream>>>(
        off_ent, packed, S1, relemb, n_ent, nbe,
        nullptr, nullptr, out_ent, nullptr,
        off_usr, sorted_i, sorted_w, su1, n_usr,
        nullptr, nullptr, out_usr, nullptr,
        eaggA, w_all);
}

// Round 9
// 492.141 us; speedup vs baseline: 3.3075x; 1.0782x over previous
//
#include <hip/hip_runtime.h>

// ---------- helpers ----------

__device__ __forceinline__ float red16(float p) {
    p += __shfl_xor(p, 1, 64);
    p += __shfl_xor(p, 2, 64);
    p += __shfl_xor(p, 4, 64);
    p += __shfl_xor(p, 8, 64);
    return p;
}

__device__ __forceinline__ float bf2f(unsigned short v) {
    return __uint_as_float(((unsigned int)v) << 16);
}
__device__ __forceinline__ unsigned short f2bf(float f) {
    unsigned int u = __float_as_uint(f);
    u = (u + 0x7FFFu + ((u >> 16) & 1u)) >> 16;
    return (unsigned short)u;
}

__device__ __forceinline__ void kgfma(float4& a, float wj, ushort4 u, float4 v) {
    a.x = fmaf(wj, bf2f(u.x) * v.x, a.x);
    a.y = fmaf(wj, bf2f(u.y) * v.y, a.y);
    a.z = fmaf(wj, bf2f(u.z) * v.z, a.z);
    a.w = fmaf(wj, bf2f(u.w) * v.w, a.w);
}
__device__ __forceinline__ void uifma(float4& a, float wj, ushort4 u) {
    a.x = fmaf(wj, bf2f(u.x), a.x);
    a.y = fmaf(wj, bf2f(u.y), a.y);
    a.z = fmaf(wj, bf2f(u.z), a.z);
    a.w = fmaf(wj, bf2f(u.w), a.w);
}

// ---------- setup kernels ----------

// 640 threads: thread = r*64+k. w_all[r][k] = sum_c W_Q[k][c]*relemb[r][c]
// (r<9); w_all[9][k] = sum_c W_UI[k][c]*relemb[etype[E-1]-1][c].
__global__ void compute_w_kernel(const float* __restrict__ WQ,
                                 const float* __restrict__ WUI,
                                 const float* __restrict__ relemb,
                                 const int* __restrict__ etype, int Ekg,
                                 float* __restrict__ w_all) {
    int tid = threadIdx.x;
    if (tid >= 640) return;
    int r = tid >> 6, k = tid & 63;
    const float* M = (r == 9) ? WUI : WQ;
    int rr = (r == 9) ? (etype[Ekg - 1] - 1) : r;
    float acc = 0.f;
#pragma unroll
    for (int c = 0; c < 64; ++c)
        acc = fmaf(M[k * 64 + c], relemb[rr * 64 + c], acc);
    w_all[r * 64 + k] = acc;
}

// merged tables: blocks [0,nbe) entity S (10 dots) + bf16 copy of E;
// [nbe,nbe+nbu) user su
__global__ void tables_kernel(const float* __restrict__ E, int n_ent, int nbe,
                              const float* __restrict__ U, int n_usr,
                              const float* __restrict__ w_all,
                              float* __restrict__ S, float* __restrict__ su,
                              unsigned short* __restrict__ Ebf) {
    __shared__ float4 w4[160];
    for (int i = threadIdx.x; i < 160; i += blockDim.x)
        w4[i] = ((const float4*)w_all)[i];
    __syncthreads();
    int l16 = threadIdx.x & 15;
    if ((int)blockIdx.x < nbe) {
        int row = blockIdx.x * 16 + (threadIdx.x >> 4);
        float4 ev = make_float4(0.f, 0.f, 0.f, 0.f);
        if (row < n_ent) ev = ((const float4*)E)[(size_t)row * 16 + l16];
        if (row < n_ent) {
            ushort4 eb;
            eb.x = f2bf(ev.x); eb.y = f2bf(ev.y);
            eb.z = f2bf(ev.z); eb.w = f2bf(ev.w);
            ((ushort4*)Ebf)[(size_t)row * 16 + l16] = eb;
        }
#pragma unroll
        for (int r = 0; r < 10; ++r) {
            float4 wv = w4[r * 16 + l16];
            float p = ev.x * wv.x + ev.y * wv.y + ev.z * wv.z + ev.w * wv.w;
            p = red16(p);
            if (l16 == 0 && row < n_ent) S[(size_t)row * 10 + r] = p;
        }
    } else {
        int row = (blockIdx.x - nbe) * 16 + (threadIdx.x >> 4);
        float4 ev = make_float4(0.f, 0.f, 0.f, 0.f);
        if (row < n_usr) ev = ((const float4*)U)[(size_t)row * 16 + l16];
        float4 wv = w4[144 + l16];
        float p = ev.x * wv.x + ev.y * wv.y + ev.z * wv.z + ev.w * wv.w;
        p = red16(p);
        if (l16 == 0 && row < n_usr) su[row] = p;
    }
}

// ---------- CSR build (merged ent+usr) ----------

__global__ void hist2_kernel(const int* __restrict__ ia, int Ea,
                             unsigned int* __restrict__ dega,
                             const int* __restrict__ ib, int Eb,
                             unsigned int* __restrict__ degb) {
    int e = blockIdx.x * blockDim.x + threadIdx.x;
    if (e < Ea) atomicAdd(&dega[ia[e]], 1u);
    else if (e < Ea + Eb) atomicAdd(&degb[ib[e - Ea]], 1u);
}

#define SCAN_CHUNK 2048

__device__ __forceinline__ void scan1_body(const unsigned int* deg, int n,
                                           unsigned int* bsums, int blk) {
    int base = blk * SCAN_CHUNK;
    int tid = threadIdx.x;
    unsigned int s = 0;
#pragma unroll
    for (int j = 0; j < 8; ++j) {
        int i = base + tid * 8 + j;
        if (i < n) s += deg[i];
    }
#pragma unroll
    for (int off = 32; off > 0; off >>= 1)
        s += __shfl_xor(s, off, 64);
    __shared__ unsigned int wsm[4];
    if ((tid & 63) == 0) wsm[tid >> 6] = s;
    __syncthreads();
    if (tid == 0) bsums[blk] = wsm[0] + wsm[1] + wsm[2] + wsm[3];
}

__global__ void scan_pass1(const unsigned int* __restrict__ dega, int na, int nba,
                           unsigned int* __restrict__ bsa,
                           const unsigned int* __restrict__ degb, int nb_,
                           unsigned int* __restrict__ bsb) {
    if ((int)blockIdx.x < nba) scan1_body(dega, na, bsa, blockIdx.x);
    else scan1_body(degb, nb_, bsb, blockIdx.x - nba);
}

__device__ __forceinline__ void scan2_body(unsigned int* bsums, int nb) {
    __shared__ unsigned int tmp[1024];
    int tid = threadIdx.x;
    unsigned int v = (tid < nb) ? bsums[tid] : 0u;
    tmp[tid] = v;
    __syncthreads();
    for (int s = 1; s < 1024; s <<= 1) {
        unsigned int add = (tid >= s) ? tmp[tid - s] : 0u;
        __syncthreads();
        tmp[tid] += add;
        __syncthreads();
    }
    if (tid < nb) bsums[tid] = tmp[tid] - v; // exclusive
}

__global__ void scan_pass2(unsigned int* __restrict__ bsa, int nba,
                           unsigned int* __restrict__ bsb, int nbb) {
    if (blockIdx.x == 0) scan2_body(bsa, nba);
    else scan2_body(bsb, nbb);
}

__device__ __forceinline__ void scan3_body(const unsigned int* deg, int n,
                                           const unsigned int* bsums,
                                           unsigned int* off, int blk) {
    int base = blk * SCAN_CHUNK;
    int tid = threadIdx.x;
    int lane = tid & 63, wv = tid >> 6;
    unsigned int x[8];
    unsigned int s = 0;
#pragma unroll
    for (int j = 0; j < 8; ++j) {
        int i = base + tid * 8 + j;
        x[j] = (i < n) ? deg[i] : 0u;
        s += x[j];
    }
    unsigned int sc = s;
#pragma unroll
    for (int o = 1; o < 64; o <<= 1) {
        unsigned int t = __shfl_up(sc, o, 64);
        if (lane >= o) sc += t;
    }
    __shared__ unsigned int wtot[4];
    if (lane == 63) wtot[wv] = sc;
    __syncthreads();
    unsigned int woff = 0;
    for (int w = 0; w < wv; ++w) woff += wtot[w];
    unsigned int run = bsums[blk] + woff + (sc - s);
#pragma unroll
    for (int j = 0; j < 8; ++j) {
        int i = base + tid * 8 + j;
        run += x[j];
        if (i < n) off[i + 1] = run;
    }
    if (blk == 0 && tid == 0) off[0] = 0;
}

__global__ void scan_pass3(const unsigned int* __restrict__ dega, int na, int nba,
                           const unsigned int* __restrict__ bsa,
                           unsigned int* __restrict__ offa,
                           const unsigned int* __restrict__ degb, int nb_,
                           const unsigned int* __restrict__ bsb,
                           unsigned int* __restrict__ offb) {
    if ((int)blockIdx.x < nba) scan3_body(dega, na, bsa, offa, blockIdx.x);
    else scan3_body(degb, nb_, bsb, offb, blockIdx.x - nba);
}

__global__ void scatter2_kernel(const int* __restrict__ head,
                                const int* __restrict__ tail,
                                const int* __restrict__ etype, int Ekg,
                                const unsigned int* __restrict__ off_e,
                                unsigned int* __restrict__ cur_e,
                                unsigned int* __restrict__ packed,
                                const int* __restrict__ uu,
                                const int* __restrict__ ii,
                                const float* __restrict__ iw, int Eui,
                                const unsigned int* __restrict__ off_u,
                                unsigned int* __restrict__ cur_u,
                                unsigned int* __restrict__ sorted_i,
                                float* __restrict__ sorted_w) {
    int e = blockIdx.x * blockDim.x + threadIdx.x;
    if (e < Ekg) {
        int h = head[e];
        unsigned int pos = off_e[h] + atomicAdd(&cur_e[h], 1u);
        packed[pos] = (unsigned int)tail[e] | (((unsigned int)(etype[e] - 1)) << 20);
    } else if (e < Ekg + Eui) {
        int e2 = e - Ekg;
        int u = uu[e2];
        unsigned int pos = off_u[u] + atomicAdd(&cur_u[u], 1u);
        sorted_i[pos] = (unsigned int)ii[e2];
        sorted_w[pos] = iw[e2];
    }
}

// ---------- fused per-hop aggregation: kg blocks then ui blocks ----------
// 16-lane group per destination row; chunked lane-parallel scoring; 4x
// unrolled bf16 row-gather (128 B/row). No max-subtraction (scores
// bounded; exp safe in fp32 — verified R7/R8).

__global__ void hop_fused_kernel(
    const unsigned int* __restrict__ off_e,
    const unsigned int* __restrict__ packed,
    const float* __restrict__ S,
    const float* __restrict__ relemb,
    int n_ent, int nbe,
    unsigned short* __restrict__ eagg_bf, float* __restrict__ Snext,
    float* __restrict__ res_e, const float* __restrict__ res_init_e,
    const unsigned int* __restrict__ off_u,
    const unsigned int* __restrict__ sorted_i,
    const float* __restrict__ sorted_w,
    const float* __restrict__ su, int n_usr,
    float* __restrict__ sunext,
    float* __restrict__ res_u, const float* __restrict__ res_init_u,
    const unsigned short* __restrict__ Ebf,
    const float* __restrict__ w_all) {
    __shared__ float4 rel4[144]; // 9 x 16
    __shared__ float4 w4[160];   // 10 x 16
    for (int i = threadIdx.x; i < 144; i += blockDim.x)
        rel4[i] = ((const float4*)relemb)[i];
    for (int i = threadIdx.x; i < 160; i += blockDim.x)
        w4[i] = ((const float4*)w_all)[i];
    __syncthreads();

    int lane = threadIdx.x & 63;
    int l16 = lane & 15;
    int gbase = lane & 48; // group base within wave for shfl

    if ((int)blockIdx.x < nbe) {
        int h = blockIdx.x * 16 + (threadIdx.x >> 4);
        if (h >= n_ent) return;
        unsigned int s0 = off_e[h], s1 = off_e[h + 1];
        float shv = (l16 < 10) ? S[(size_t)h * 10 + l16] : 0.f;

        float4 a0 = make_float4(0.f, 0.f, 0.f, 0.f);
        float4 a1 = make_float4(0.f, 0.f, 0.f, 0.f);
        float4 a2 = make_float4(0.f, 0.f, 0.f, 0.f);
        float4 a3 = make_float4(0.f, 0.f, 0.f, 0.f);
        float wsum = 0.f;
        for (unsigned int base = s0; base < s1; base += 16) {
            unsigned int rem = s1 - base;
            unsigned int c = rem < 16u ? rem : 16u;
            unsigned int pk = (l16 < (int)c) ? packed[base + l16] : 0u;
            int t = pk & 0xFFFFF, r = pk >> 20;
            float st = S[(size_t)t * 10 + r];
            float q = __shfl(shv, gbase + r, 64);
            float wg = (l16 < (int)c) ? __expf(q + st) : 0.f;
            wsum += red16(wg);
            unsigned int j = 0;
            for (; j + 4 <= c; j += 4) {
                unsigned int p0 = (unsigned int)__shfl((int)pk, gbase + (int)j, 64);
                unsigned int p1 = (unsigned int)__shfl((int)pk, gbase + (int)j + 1, 64);
                unsigned int p2 = (unsigned int)__shfl((int)pk, gbase + (int)j + 2, 64);
                unsigned int p3 = (unsigned int)__shfl((int)pk, gbase + (int)j + 3, 64);
                float w0 = __shfl(wg, gbase + (int)j, 64);
                float w1 = __shfl(wg, gbase + (int)j + 1, 64);
                float w2 = __shfl(wg, gbase + (int)j + 2, 64);
                float w3 = __shfl(wg, gbase + (int)j + 3, 64);
                int t0 = p0 & 0xFFFFF, t1 = p1 & 0xFFFFF;
                int t2 = p2 & 0xFFFFF, t3 = p3 & 0xFFFFF;
                ushort4 u0 = ((const ushort4*)Ebf)[(size_t)t0 * 16 + l16];
                ushort4 u1 = ((const ushort4*)Ebf)[(size_t)t1 * 16 + l16];
                ushort4 u2 = ((const ushort4*)Ebf)[(size_t)t2 * 16 + l16];
                ushort4 u3 = ((const ushort4*)Ebf)[(size_t)t3 * 16 + l16];
                kgfma(a0, w0, u0, rel4[(p0 >> 20) * 16 + l16]);
                kgfma(a1, w1, u1, rel4[(p1 >> 20) * 16 + l16]);
                kgfma(a2, w2, u2, rel4[(p2 >> 20) * 16 + l16]);
                kgfma(a3, w3, u3, rel4[(p3 >> 20) * 16 + l16]);
            }
            for (; j < c; ++j) {
                unsigned int p0 = (unsigned int)__shfl((int)pk, gbase + (int)j, 64);
                float w0 = __shfl(wg, gbase + (int)j, 64);
                int t0 = p0 & 0xFFFFF;
                ushort4 u0 = ((const ushort4*)Ebf)[(size_t)t0 * 16 + l16];
                kgfma(a0, w0, u0, rel4[(p0 >> 20) * 16 + l16]);
            }
        }
        float4 acc = make_float4(a0.x + a1.x + a2.x + a3.x,
                                 a0.y + a1.y + a2.y + a3.y,
                                 a0.z + a1.z + a2.z + a3.z,
                                 a0.w + a1.w + a2.w + a3.w);
        float inv = 1.f / (wsum + 1e-16f);
        float4 y = make_float4(acc.x * inv, acc.y * inv, acc.z * inv, acc.w * inv);
        float ss = red16(y.x * y.x + y.y * y.y + y.z * y.z + y.w * y.w);
        float sinv = 1.f / fmaxf(sqrtf(ss), 1e-12f);
        y.x *= sinv; y.y *= sinv; y.z *= sinv; y.w *= sinv;

        size_t ro = (size_t)h * 16 + l16;
        if (eagg_bf) {
            ushort4 yb;
            yb.x = f2bf(y.x); yb.y = f2bf(y.y);
            yb.z = f2bf(y.z); yb.w = f2bf(y.w);
            ((ushort4*)eagg_bf)[ro] = yb;
        }
        float4 b4 = res_init_e ? ((const float4*)res_init_e)[ro]
                               : ((const float4*)res_e)[ro];
        ((float4*)res_e)[ro] = make_float4(b4.x + y.x, b4.y + y.y,
                                           b4.z + y.z, b4.w + y.w);
        if (Snext) {
#pragma unroll
            for (int r2 = 0; r2 < 10; ++r2) {
                float4 wv = w4[r2 * 16 + l16];
                float p = red16(y.x * wv.x + y.y * wv.y + y.z * wv.z + y.w * wv.w);
                if (l16 == 0) Snext[(size_t)h * 10 + r2] = p;
            }
        }
    } else {
        int u = (blockIdx.x - nbe) * 16 + (threadIdx.x >> 4);
        if (u >= n_usr) return;
        unsigned int s0 = off_u[u], s1 = off_u[u + 1];
        float squ = su[u];

        float4 a0 = make_float4(0.f, 0.f, 0.f, 0.f);
        float4 a1 = make_float4(0.f, 0.f, 0.f, 0.f);
        float4 a2 = make_float4(0.f, 0.f, 0.f, 0.f);
        float4 a3 = make_float4(0.f, 0.f, 0.f, 0.f);
        float wsum = 0.f;
        for (unsigned int base = s0; base < s1; base += 16) {
            unsigned int rem = s1 - base;
            unsigned int c = rem < 16u ? rem : 16u;
            unsigned int iv = 0; float wg = 0.f, cw = 0.f;
            if (l16 < (int)c) {
                iv = sorted_i[base + l16];
                float sw = sorted_w[base + l16];
                wg = __expf(squ + S[(size_t)iv * 10 + 9]);
                cw = wg * sw;
            }
            wsum += red16(wg);
            unsigned int j = 0;
            for (; j + 4 <= c; j += 4) {
                unsigned int i0 = (unsigned int)__shfl((int)iv, gbase + (int)j, 64);
                unsigned int i1 = (unsigned int)__shfl((int)iv, gbase + (int)j + 1, 64);
                unsigned int i2 = (unsigned int)__shfl((int)iv, gbase + (int)j + 2, 64);
                unsigned int i3 = (unsigned int)__shfl((int)iv, gbase + (int)j + 3, 64);
                float w0 = __shfl(cw, gbase + (int)j, 64);
                float w1 = __shfl(cw, gbase + (int)j + 1, 64);
                float w2 = __shfl(cw, gbase + (int)j + 2, 64);
                float w3 = __shfl(cw, gbase + (int)j + 3, 64);
                ushort4 u0 = ((const ushort4*)Ebf)[(size_t)i0 * 16 + l16];
                ushort4 u1 = ((const ushort4*)Ebf)[(size_t)i1 * 16 + l16];
                ushort4 u2 = ((const ushort4*)Ebf)[(size_t)i2 * 16 + l16];
                ushort4 u3 = ((const ushort4*)Ebf)[(size_t)i3 * 16 + l16];
                uifma(a0, w0, u0);
                uifma(a1, w1, u1);
                uifma(a2, w2, u2);
                uifma(a3, w3, u3);
            }
            for (; j < c; ++j) {
                unsigned int i0 = (unsigned int)__shfl((int)iv, gbase + (int)j, 64);
                float w0 = __shfl(cw, gbase + (int)j, 64);
                ushort4 u0 = ((const ushort4*)Ebf)[(size_t)i0 * 16 + l16];
                uifma(a0, w0, u0);
            }
        }
        float4 acc = make_float4(a0.x + a1.x + a2.x + a3.x,
                                 a0.y + a1.y + a2.y + a3.y,
                                 a0.z + a1.z + a2.z + a3.z,
                                 a0.w + a1.w + a2.w + a3.w);
        float inv = 1.f / (wsum + 1e-16f);
        float4 y = make_float4(acc.x * inv, acc.y * inv, acc.z * inv, acc.w * inv);
        float ss = red16(y.x * y.x + y.y * y.y + y.z * y.z + y.w * y.w);
        float sinv = 1.f / fmaxf(sqrtf(ss), 1e-12f);
        y.x *= sinv; y.y *= sinv; y.z *= sinv; y.w *= sinv;

        size_t ro = (size_t)u * 16 + l16;
        float4 b4 = res_init_u ? ((const float4*)res_init_u)[ro]
                               : ((const float4*)res_u)[ro];
        ((float4*)res_u)[ro] = make_float4(b4.x + y.x, b4.y + y.y,
                                           b4.z + y.z, b4.w + y.w);
        if (sunext) {
            float4 wv = w4[144 + l16];
            float p = red16(y.x * wv.x + y.y * wv.y + y.z * wv.z + y.w * wv.w);
            if (l16 == 0) sunext[u] = p;
        }
    }
}

// ---------- launch ----------

extern "C" void kernel_launch(void* const* d_in, const int* in_sizes, int n_in,
                              void* d_out, int out_size, void* d_ws, size_t ws_size,
                              hipStream_t stream) {
    const float* user_emb   = (const float*)d_in[0];
    const float* entity_emb = (const float*)d_in[1];
    const int*   edge_index = (const int*)d_in[2];
    const int*   edge_type  = (const int*)d_in[3];
    const int*   inter_edge = (const int*)d_in[4];
    const float* inter_w    = (const float*)d_in[5];
    const float* relemb     = (const float*)d_in[6];
    const float* WQ         = (const float*)d_in[7];
    const float* WUI        = (const float*)d_in[8];

    const int C = 64;
    const int n_usr = in_sizes[0] / C;
    const int n_ent = in_sizes[1] / C;
    const int Ekg   = in_sizes[3];
    const int Eui   = in_sizes[5];
    const int* head = edge_index;
    const int* tail = edge_index + Ekg;
    const int* uu   = inter_edge;
    const int* ii   = inter_edge + Eui;

    float* ws = (float*)d_ws;
    float* w_all = ws;                          ws += 640;
    float* S0    = ws;                          ws += (size_t)n_ent * 10;
    float* S1    = ws;                          ws += (size_t)n_ent * 10;
    float* su0   = ws;                          ws += n_usr;
    float* su1   = ws;                          ws += n_usr;
    unsigned int* deg_ent = (unsigned int*)ws;  ws += n_ent;   // also cursor
    unsigned int* deg_usr = (unsigned int*)ws;  ws += n_usr;   // also cursor
    unsigned int* off_ent = (unsigned int*)ws;  ws += n_ent + 1;
    unsigned int* off_usr = (unsigned int*)ws;  ws += n_usr + 1;
    unsigned int* bsum_e  = (unsigned int*)ws;  ws += 1024;
    unsigned int* bsum_u  = (unsigned int*)ws;  ws += 1024;
    unsigned int* packed  = (unsigned int*)ws;  ws += Ekg;
    unsigned int* sorted_i = (unsigned int*)ws; ws += Eui;
    float* sorted_w = ws;                       ws += Eui + (((size_t)(Eui)) & 1);
    unsigned short* ebf0 = (unsigned short*)ws; ws += (size_t)n_ent * 32;
    unsigned short* ebf1 = (unsigned short*)ws; ws += (size_t)n_ent * 32;

    float* out_ent = (float*)d_out;
    float* out_usr = out_ent + (size_t)n_ent * C;

    compute_w_kernel<<<1, 640, 0, stream>>>(WQ, WUI, relemb, edge_type, Ekg, w_all);

    // ---- CSR build (edges static across hops) ----
    hipMemsetAsync(deg_ent, 0, (size_t)(n_ent + n_usr) * sizeof(unsigned int), stream);
    hist2_kernel<<<(Ekg + Eui + 255) / 256, 256, 0, stream>>>(
        head, Ekg, deg_ent, uu, Eui, deg_usr);

    int nb_e = (n_ent + SCAN_CHUNK - 1) / SCAN_CHUNK;
    int nb_u = (n_usr + SCAN_CHUNK - 1) / SCAN_CHUNK;
    scan_pass1<<<nb_e + nb_u, 256, 0, stream>>>(deg_ent, n_ent, nb_e, bsum_e,
                                                deg_usr, n_usr, bsum_u);
    scan_pass2<<<2, 1024, 0, stream>>>(bsum_e, nb_e, bsum_u, nb_u);
    scan_pass3<<<nb_e + nb_u, 256, 0, stream>>>(deg_ent, n_ent, nb_e, bsum_e, off_ent,
                                                deg_usr, n_usr, bsum_u, off_usr);

    hipMemsetAsync(deg_ent, 0, (size_t)(n_ent + n_usr) * sizeof(unsigned int), stream);
    scatter2_kernel<<<(Ekg + Eui + 255) / 256, 256, 0, stream>>>(
        head, tail, edge_type, Ekg, off_ent, deg_ent, packed,
        uu, ii, inter_w, Eui, off_usr, deg_usr, sorted_i, sorted_w);

    int nbe = (n_ent + 15) / 16;
    int nbu = (n_usr + 15) / 16;

    // ---- hop-0 tables + bf16 copy of entity_emb ----
    tables_kernel<<<nbe + nbu, 256, 0, stream>>>(
        entity_emb, n_ent, nbe, user_emb, n_usr, w_all, S0, su0, ebf0);

    // ---- hop 0: emits S1/su1 + bf16 agg for hop 1; res = init + y ----
    hop_fused_kernel<<<nbe + nbu, 256, 0, stream>>>(
        off_ent, packed, S0, relemb, n_ent, nbe,
        ebf1, S1, out_ent, entity_emb,
        off_usr, sorted_i, sorted_w, su0, n_usr,
        su1, out_usr, user_emb,
        ebf0, w_all);

    // ---- hop 1: res += y (agg outputs dead -> skipped) ----
    hop_fused_kernel<<<nbe + nbu, 256, 0, stream>>>(
        off_ent, packed, S1, relemb, n_ent, nbe,
        nullptr, nullptr, out_ent, nullptr,
        off_usr, sorted_i, sorted_w, su1, n_usr,
        nullptr, out_usr, nullptr,
        ebf1, w_all);
}